// Round 1
// baseline (3611.568 us; speedup 1.0000x reference)
//
#include <hip/hip_runtime.h>

#define DEV __device__ __forceinline__

typedef __attribute__((ext_vector_type(4))) float f32x4;
typedef __attribute__((ext_vector_type(8))) short short8_t;

constexpr int LNUM = 6;
constexpr int BB = 4;
constexpr int SS = 1024;
constexpr int DD = 1024;
constexpr int HH = 16;
constexpr int HDD = 64;
constexpr int FF = 4096;
constexpr int VV = 32000;
constexpr int MROWS = BB * SS;   // 4096

DEV short f2bf(float f) {
  union { float f; unsigned u; } x; x.f = f;
  unsigned r = x.u + 0x7fffu + ((x.u >> 16) & 1u);   // RNE
  return (short)(r >> 16);
}

// ---------------- embedding: x = tok_emb[tok] + pos_emb ----------------
__global__ __launch_bounds__(256) void k_embed(
    const int* __restrict__ tok, const float* __restrict__ te,
    const float* __restrict__ pe, float* __restrict__ xf,
    short* __restrict__ xb) {
  int i = blockIdx.x * 256 + threadIdx.x;            // over MROWS*DD/4
  int bs = i >> 8, d4 = i & 255;
  int t = tok[bs];
  float4 a = ((const float4*)(te + (size_t)t * DD))[d4];
  float4 b = ((const float4*)(pe + (size_t)(bs & (SS - 1)) * DD))[d4];
  float4 r; r.x = a.x + b.x; r.y = a.y + b.y; r.z = a.z + b.z; r.w = a.w + b.w;
  ((float4*)xf)[i] = r;
  short4 o; o.x = f2bf(r.x); o.y = f2bf(r.y); o.z = f2bf(r.z); o.w = f2bf(r.w);
  ((short4*)xb)[i] = o;
}

// ------------- transpose + fp32->bf16: W[K,N] -> Wt[N,K] bf16 -------------
__global__ __launch_bounds__(256) void k_tcvt(
    const float* __restrict__ in, short* __restrict__ out, int K, int N) {
  __shared__ float tile[32][33];
  const float* ip = in + (size_t)blockIdx.z * K * N;
  short* op = out + (size_t)blockIdx.z * K * N;
  int bn = blockIdx.x * 32, bk = blockIdx.y * 32;
  int tx = threadIdx.x, ty = threadIdx.y;            // (32,8)
  #pragma unroll
  for (int r = 0; r < 32; r += 8)
    tile[ty + r][tx] = ip[(size_t)(bk + ty + r) * N + bn + tx];
  __syncthreads();
  #pragma unroll
  for (int r = 0; r < 32; r += 8)
    op[(size_t)(bn + ty + r) * K + bk + tx] = f2bf(tile[tx][ty + r]);
}

// ---------------- bf16 MFMA GEMM, 128x128 tile, BK=32 ----------------
// A[M,K] row-major bf16 (lda), Bt[N,K] row-major bf16 (ldb), batched by z.
// MODE epilogues (fixed model dims hardcoded):
//  1: q/k -> [B,H,S,HD]    2: v -> [B,H,HD,S]
//  3: scores fp32 *0.125, batch z=(b,h), causal block-skip
//  4: PV out -> o[b,s,h*HD+c] (N=64 guarded, K clipped to causal prefix)
//  5: fp32 [M,N]           6: bf16 relu(x+bias)      7: fp32 x+bias
DEV void gload16(const short* g, short* l) {
  __builtin_amdgcn_global_load_lds(
      (const __attribute__((address_space(1))) void*)g,
      (__attribute__((address_space(3))) void*)l, 16, 0, 0);
}

template<int MODE>
__global__ __launch_bounds__(256) void k_gemm(
    const short* __restrict__ A, const short* __restrict__ Bt,
    const float* __restrict__ bias, void* __restrict__ Cp,
    int M, int N, int K, int lda, int ldb,
    long long bsA, long long bsB) {
  __shared__ short lA[4096];
  __shared__ short lB[4096];
  const int tid = threadIdx.x;
  const int z = blockIdx.z;
  const short* Ap = A + (size_t)z * bsA;
  const short* Bp = Bt + (size_t)z * bsB;
  const int n0 = blockIdx.x * 128, m0 = blockIdx.y * 128;
  if (MODE == 3 && n0 > m0 + 127) return;            // fully-masked block
  int Kend = K;
  if (MODE == 4) Kend = min(K, m0 + 128);            // probs zero past diag

  const int lane = tid & 63;
  const int wm = (tid >> 6) >> 1, wn = (tid >> 6) & 1;
  const int l16 = lane & 15, kg = lane >> 4;
  const int srow = tid >> 2, scol = (tid & 3) * 8;   // staging: 64 rows x 32 cols /issue
  const int lbase = (tid & ~63) * 8;                 // wave-uniform LDS elem base

  f32x4 acc[4][4];
  #pragma unroll
  for (int a = 0; a < 4; a++)
    #pragma unroll
    for (int b = 0; b < 4; b++)
      #pragma unroll
      for (int j = 0; j < 4; j++) acc[a][b][j] = 0.f;

  for (int k0 = 0; k0 < Kend; k0 += 32) {
    #pragma unroll
    for (int i = 0; i < 2; i++) {
      const short* gp = Ap + (size_t)(m0 + i * 64 + srow) * lda + (k0 + scol);
      gload16(gp, &lA[i * 2048 + lbase]);
    }
    #pragma unroll
    for (int i = 0; i < 2; i++) {
      int gr = n0 + i * 64 + srow; gr = min(gr, N - 1);   // PV N=64 clamp
      const short* gp = Bp + (size_t)gr * ldb + (k0 + scol);
      gload16(gp, &lB[i * 2048 + lbase]);
    }
    __syncthreads();                                  // drains vmcnt (m97 pattern)
    short8_t af[4], bf[4];
    #pragma unroll
    for (int mi = 0; mi < 4; mi++)
      af[mi] = *(const short8_t*)&lA[(wm * 64 + mi * 16 + l16) * 32 + kg * 8];
    #pragma unroll
    for (int ni = 0; ni < 4; ni++)
      bf[ni] = *(const short8_t*)&lB[(wn * 64 + ni * 16 + l16) * 32 + kg * 8];
    #pragma unroll
    for (int mi = 0; mi < 4; mi++)
      #pragma unroll
      for (int ni = 0; ni < 4; ni++)
        acc[mi][ni] = __builtin_amdgcn_mfma_f32_16x16x32_bf16(
            af[mi], bf[ni], acc[mi][ni], 0, 0, 0);
    __syncthreads();
  }

  #pragma unroll
  for (int mi = 0; mi < 4; mi++) {
    #pragma unroll
    for (int ni = 0; ni < 4; ni++) {
      #pragma unroll
      for (int j = 0; j < 4; j++) {
        const int r = m0 + wm * 64 + mi * 16 + kg * 4 + j;   // C/D row (m89)
        const int c = n0 + wn * 64 + ni * 16 + l16;          // C/D col
        const float v = acc[mi][ni][j];
        if (MODE == 1) {
          int b = r >> 10, s = r & 1023, h = c >> 6, hd = c & 63;
          ((short*)Cp)[(((size_t)(b * HH + h) << 10) + s) * HDD + hd] = f2bf(v);
        } else if (MODE == 2) {
          int b = r >> 10, s = r & 1023, h = c >> 6, hd = c & 63;
          ((short*)Cp)[(((size_t)(b * HH + h) * HDD + hd) << 10) + s] = f2bf(v);
        } else if (MODE == 3) {
          ((float*)Cp)[((size_t)z << 20) + (size_t)r * SS + c] = v * 0.125f;
        } else if (MODE == 4) {
          if (c < N) {
            int b = z >> 4, h = z & 15;
            ((short*)Cp)[((size_t)(b * SS + r)) * DD + h * HDD + c] = f2bf(v);
          }
        } else if (MODE == 5) {
          ((float*)Cp)[(size_t)r * N + c] = v;
        } else if (MODE == 6) {
          ((short*)Cp)[(size_t)r * N + c] = f2bf(fmaxf(v + bias[c], 0.f));
        } else if (MODE == 7) {
          ((float*)Cp)[(size_t)r * N + c] = v + bias[c];
        }
      }
    }
  }
}

// ---------------- causal row softmax: fp32 scores -> bf16 probs ----------------
__global__ __launch_bounds__(256) void k_softmax(
    const float* __restrict__ sc, short* __restrict__ pb) {
  const int row = blockIdx.x;                 // bh*1024 + s
  const int s = row & 1023;
  const int tid = threadIdx.x;
  float4 v = ((const float4*)(sc + ((size_t)row << 10)))[tid];
  float vv[4] = {v.x, v.y, v.z, v.w};
  const int base = tid * 4, len = s + 1;
  float m = -1e30f;
  #pragma unroll
  for (int j = 0; j < 4; j++) if (base + j < len) m = fmaxf(m, vv[j]);
  #pragma unroll
  for (int o = 32; o; o >>= 1) m = fmaxf(m, __shfl_xor(m, o));
  __shared__ float sh1[4], sh2[4];
  if ((tid & 63) == 0) sh1[tid >> 6] = m;
  __syncthreads();
  m = fmaxf(fmaxf(sh1[0], sh1[1]), fmaxf(sh1[2], sh1[3]));
  float e[4]; float lsum = 0.f;
  #pragma unroll
  for (int j = 0; j < 4; j++) {
    e[j] = (base + j < len) ? __expf(vv[j] - m) : 0.f;
    lsum += e[j];
  }
  #pragma unroll
  for (int o = 32; o; o >>= 1) lsum += __shfl_xor(lsum, o);
  if ((tid & 63) == 0) sh2[tid >> 6] = lsum;
  __syncthreads();
  float inv = 1.f / (sh2[0] + sh2[1] + sh2[2] + sh2[3]);
  short4 o4; o4.x = f2bf(e[0] * inv); o4.y = f2bf(e[1] * inv);
  o4.z = f2bf(e[2] * inv); o4.w = f2bf(e[3] * inv);
  ((short4*)(pb + ((size_t)row << 10)))[tid] = o4;
}

// ---------------- LayerNorm (D=1024) with optional residual ----------------
template<int ADD_RES, int WRITE_F32>
__global__ __launch_bounds__(256) void k_ln(
    const float* __restrict__ src, const float* __restrict__ res,
    const float* __restrict__ g, const float* __restrict__ b,
    float* __restrict__ of, short* __restrict__ ob) {
  const int row = blockIdx.x;
  const int tid = threadIdx.x;
  float4 v = ((const float4*)(src + ((size_t)row << 10)))[tid];
  float s1 = v.x + v.y + v.z + v.w;
  float s2 = v.x * v.x + v.y * v.y + v.z * v.z + v.w * v.w;
  #pragma unroll
  for (int o = 32; o; o >>= 1) { s1 += __shfl_xor(s1, o); s2 += __shfl_xor(s2, o); }
  __shared__ float sh1[4], sh2[4];
  if ((tid & 63) == 0) { sh1[tid >> 6] = s1; sh2[tid >> 6] = s2; }
  __syncthreads();
  s1 = sh1[0] + sh1[1] + sh1[2] + sh1[3];
  s2 = sh2[0] + sh2[1] + sh2[2] + sh2[3];
  const float mean = s1 * (1.f / 1024.f);
  const float var  = s2 * (1.f / 1024.f) - mean * mean;
  const float rs = rsqrtf(var + 1e-5f);
  float4 gg = ((const float4*)g)[tid];
  float4 bb = ((const float4*)b)[tid];
  float4 o4;
  o4.x = (v.x - mean) * rs * gg.x + bb.x;
  o4.y = (v.y - mean) * rs * gg.y + bb.y;
  o4.z = (v.z - mean) * rs * gg.z + bb.z;
  o4.w = (v.w - mean) * rs * gg.w + bb.w;
  if (ADD_RES) {
    float4 rr = ((const float4*)(res + ((size_t)row << 10)))[tid];
    o4.x += rr.x; o4.y += rr.y; o4.z += rr.z; o4.w += rr.w;
  }
  if (WRITE_F32) ((float4*)(of + ((size_t)row << 10)))[tid] = o4;
  short4 s4; s4.x = f2bf(o4.x); s4.y = f2bf(o4.y);
  s4.z = f2bf(o4.z); s4.w = f2bf(o4.w);
  ((short4*)ob)[((size_t)row << 8) + tid] = s4;
}

extern "C" void kernel_launch(void* const* d_in, const int* in_sizes, int n_in,
                              void* d_out, int out_size, void* d_ws, size_t ws_size,
                              hipStream_t stream) {
  (void)in_sizes; (void)n_in; (void)out_size; (void)ws_size;
  const int*   tokens  = (const int*)d_in[0];
  const float* tok_emb = (const float*)d_in[1];
  const float* pos_emb = (const float*)d_in[2];
  const float* Wq = (const float*)d_in[3];
  const float* Wk = (const float*)d_in[4];
  const float* Wv = (const float*)d_in[5];
  const float* Wp = (const float*)d_in[6];
  const float* ln1s = (const float*)d_in[7];
  const float* ln1b = (const float*)d_in[8];
  const float* W1 = (const float*)d_in[9];
  const float* b1 = (const float*)d_in[10];
  const float* W2 = (const float*)d_in[11];
  const float* b2 = (const float*)d_in[12];
  const float* ln2s = (const float*)d_in[13];
  const float* ln2b = (const float*)d_in[14];
  const float* lnfs = (const float*)d_in[15];
  const float* lnfb = (const float*)d_in[16];
  const float* Wh = (const float*)d_in[17];
  const float* bh = (const float*)d_in[18];
  float* out = (float*)d_out;

  char* p = (char*)d_ws;
  auto alloc = [&](size_t elems, size_t esz) -> char* {
    char* r = p; p += (elems * esz + 255) & ~(size_t)255; return r;
  };
  short* WqT = (short*)alloc((size_t)LNUM * DD * DD, 2);
  short* WkT = (short*)alloc((size_t)LNUM * DD * DD, 2);
  short* WvT = (short*)alloc((size_t)LNUM * DD * DD, 2);
  short* WpT = (short*)alloc((size_t)LNUM * DD * DD, 2);
  short* W1T = (short*)alloc((size_t)LNUM * DD * FF, 2);
  short* W2T = (short*)alloc((size_t)LNUM * DD * FF, 2);
  short* WhT = (short*)alloc((size_t)DD * VV, 2);
  float* xf   = (float*)alloc((size_t)MROWS * DD, 4);   // fp32 residual stream
  float* ff   = (float*)alloc((size_t)MROWS * DD, 4);   // proj / ffn2 out fp32
  short* xb   = (short*)alloc((size_t)MROWS * DD, 2);   // bf16 of x
  short* ab   = (short*)alloc((size_t)MROWS * DD, 2);   // a = x + ln1(..)
  short* qb   = (short*)alloc((size_t)MROWS * DD, 2);
  short* kb   = (short*)alloc((size_t)MROWS * DD, 2);
  short* vtb  = (short*)alloc((size_t)MROWS * DD, 2);   // [B,H,HD,S]
  short* obuf = (short*)alloc((size_t)MROWS * DD, 2);
  short* hb   = (short*)alloc((size_t)MROWS * FF, 2);   // ffn hidden bf16
  short* xfb  = (short*)alloc((size_t)MROWS * DD, 2);   // lnf(x) bf16
  float* scor = (float*)alloc((size_t)BB * HH * SS * SS, 4);
  short* prob = (short*)alloc((size_t)BB * HH * SS * SS, 2);

  dim3 blk(256);
  dim3 t8(32, 8);
  // weight convert+transpose (per call; deterministic)
  k_tcvt<<<dim3(DD / 32, DD / 32, LNUM), t8, 0, stream>>>(Wq, WqT, DD, DD);
  k_tcvt<<<dim3(DD / 32, DD / 32, LNUM), t8, 0, stream>>>(Wk, WkT, DD, DD);
  k_tcvt<<<dim3(DD / 32, DD / 32, LNUM), t8, 0, stream>>>(Wv, WvT, DD, DD);
  k_tcvt<<<dim3(DD / 32, DD / 32, LNUM), t8, 0, stream>>>(Wp, WpT, DD, DD);
  k_tcvt<<<dim3(FF / 32, DD / 32, LNUM), t8, 0, stream>>>(W1, W1T, DD, FF);
  k_tcvt<<<dim3(DD / 32, FF / 32, LNUM), t8, 0, stream>>>(W2, W2T, FF, DD);
  k_tcvt<<<dim3(VV / 32, DD / 32, 1),   t8, 0, stream>>>(Wh, WhT, DD, VV);

  k_embed<<<(MROWS * DD / 4) / 256, blk, 0, stream>>>(tokens, tok_emb, pos_emb, xf, xb);

  for (int l = 0; l < LNUM; l++) {
    const short* wq = WqT + (size_t)l * DD * DD;
    const short* wk = WkT + (size_t)l * DD * DD;
    const short* wv = WvT + (size_t)l * DD * DD;
    const short* wp = WpT + (size_t)l * DD * DD;
    const short* w1 = W1T + (size_t)l * DD * FF;
    const short* w2 = W2T + (size_t)l * DD * FF;

    k_gemm<1><<<dim3(8, 32, 1), blk, 0, stream>>>(xb, wq, nullptr, qb,
        MROWS, DD, DD, DD, DD, 0, 0);
    k_gemm<1><<<dim3(8, 32, 1), blk, 0, stream>>>(xb, wk, nullptr, kb,
        MROWS, DD, DD, DD, DD, 0, 0);
    k_gemm<2><<<dim3(8, 32, 1), blk, 0, stream>>>(xb, wv, nullptr, vtb,
        MROWS, DD, DD, DD, DD, 0, 0);
    // scores[b,h] = q @ k^T * 0.125 (causal blocks only)
    k_gemm<3><<<dim3(8, 8, BB * HH), blk, 0, stream>>>(qb, kb, nullptr, scor,
        SS, SS, HDD, HDD, HDD, (long long)SS * HDD, (long long)SS * HDD);
    k_softmax<<<BB * HH * SS, blk, 0, stream>>>(scor, prob);
    // o[b,h] = P @ V   (A=probs [S,S], Bt=v^T [HD,S])
    k_gemm<4><<<dim3(1, 8, BB * HH), blk, 0, stream>>>(prob, vtb, nullptr, obuf,
        SS, HDD, SS, SS, SS, (long long)SS * SS, (long long)HDD * SS);
    // proj
    k_gemm<5><<<dim3(8, 32, 1), blk, 0, stream>>>(obuf, wp, nullptr, ff,
        MROWS, DD, DD, DD, DD, 0, 0);
    k_ln<1, 0><<<MROWS, blk, 0, stream>>>(ff, xf, ln1s + (size_t)l * DD,
        ln1b + (size_t)l * DD, nullptr, ab);
    // ffn
    k_gemm<6><<<dim3(32, 32, 1), blk, 0, stream>>>(ab, w1, b1 + (size_t)l * FF, hb,
        MROWS, FF, DD, DD, DD, 0, 0);
    k_gemm<7><<<dim3(8, 32, 1), blk, 0, stream>>>(hb, w2, b2 + (size_t)l * DD, ff,
        MROWS, DD, FF, FF, FF, 0, 0);
    k_ln<1, 1><<<MROWS, blk, 0, stream>>>(ff, xf, ln2s + (size_t)l * DD,
        ln2b + (size_t)l * DD, xf, xb);
  }

  k_ln<0, 0><<<MROWS, blk, 0, stream>>>(xf, nullptr, lnfs, lnfb, nullptr, xfb);
  // logits = lnf(x) @ Wh + bh
  k_gemm<7><<<dim3(VV / 128, 32, 1), blk, 0, stream>>>(xfb, WhT, bh, out,
      MROWS, VV, DD, DD, DD, 0, 0);
}

// Round 2
// 2876.746 us; speedup vs baseline: 1.2554x; 1.2554x over previous
//
#include <hip/hip_runtime.h>

#define DEV __device__ __forceinline__

typedef __attribute__((ext_vector_type(4))) float f32x4;
typedef __attribute__((ext_vector_type(8))) short short8_t;

constexpr int LNUM = 6;
constexpr int BB = 4;
constexpr int SS = 1024;
constexpr int DD = 1024;
constexpr int HH = 16;
constexpr int HDD = 64;
constexpr int FF = 4096;
constexpr int VV = 32000;
constexpr int MROWS = BB * SS;   // 4096

DEV short f2bf(float f) {
  union { float f; unsigned u; } x; x.f = f;
  unsigned r = x.u + 0x7fffu + ((x.u >> 16) & 1u);   // RNE
  return (short)(r >> 16);
}

// ---------------- embedding: x = tok_emb[tok] + pos_emb ----------------
__global__ __launch_bounds__(256) void k_embed(
    const int* __restrict__ tok, const float* __restrict__ te,
    const float* __restrict__ pe, float* __restrict__ xf,
    short* __restrict__ xb) {
  int i = blockIdx.x * 256 + threadIdx.x;            // over MROWS*DD/4
  int bs = i >> 8, d4 = i & 255;
  int t = tok[bs];
  float4 a = ((const float4*)(te + (size_t)t * DD))[d4];
  float4 b = ((const float4*)(pe + (size_t)(bs & (SS - 1)) * DD))[d4];
  float4 r; r.x = a.x + b.x; r.y = a.y + b.y; r.z = a.z + b.z; r.w = a.w + b.w;
  ((float4*)xf)[i] = r;
  short4 o; o.x = f2bf(r.x); o.y = f2bf(r.y); o.z = f2bf(r.z); o.w = f2bf(r.w);
  ((short4*)xb)[i] = o;
}

// ------- transpose + fp32->bf16: W[K,N] -> Wt[N,K] bf16, out stride per z -------
__global__ __launch_bounds__(256) void k_tcvt(
    const float* __restrict__ in, short* __restrict__ out, int K, int N,
    long long ostride) {
  __shared__ float tile[32][33];
  const float* ip = in + (size_t)blockIdx.z * K * N;
  short* op = out + (size_t)blockIdx.z * ostride;
  int bn = blockIdx.x * 32, bk = blockIdx.y * 32;
  int tx = threadIdx.x, ty = threadIdx.y;            // (32,8)
  #pragma unroll
  for (int r = 0; r < 32; r += 8)
    tile[ty + r][tx] = ip[(size_t)(bk + ty + r) * N + bn + tx];
  __syncthreads();
  #pragma unroll
  for (int r = 0; r < 32; r += 8)
    op[(size_t)(bn + ty + r) * K + bk + tx] = f2bf(tile[tx][ty + r]);
}

DEV void gload16(const short* g, short* l) {
  __builtin_amdgcn_global_load_lds(
      (const __attribute__((address_space(1))) void*)g,
      (__attribute__((address_space(3))) void*)l, 16, 0, 0);
}

// ---------------- bf16 MFMA GEMM, 128x128 tile, BK=32 ----------------
// A[M,K] row-major bf16 (lda), Bt[N,K] row-major bf16 (ldb), batched by z.
// MODE epilogues:
//  4: PV out -> o[b,s,h*HD+c] (N=64 guarded, K clipped to causal prefix)
//  5: fp32 [M,N]      6: bf16 relu(x+bias)      7: fp32 x+bias
//  8: fused QKV: c<1024 -> q[B,H,S,HD]; <2048 -> k; else v^T[B,H,HD,S]
//  9: like 7 with XCD-bijective block swizzle (logits)
template<int MODE>
__global__ __launch_bounds__(256) void k_gemm(
    const short* __restrict__ A, const short* __restrict__ Bt,
    const float* __restrict__ bias, void* __restrict__ Cp,
    int M, int N, int K, int lda, int ldb,
    long long bsA, long long bsB) {
  __shared__ short lA[4096];
  __shared__ short lB[4096];
  const int tid = threadIdx.x;
  const int z = blockIdx.z;
  const short* Ap = A + (size_t)z * bsA;
  const short* Bp = Bt + (size_t)z * bsB;
  int bx = blockIdx.x, by = blockIdx.y;
  if (MODE == 9) {                                    // XCD swizzle (nwg%8==0)
    int nbx = gridDim.x;
    int orig = by * nbx + bx;
    int cpx = (nbx * gridDim.y) >> 3;
    int wg = (orig & 7) * cpx + (orig >> 3);
    by = wg / nbx; bx = wg - by * nbx;
  }
  const int n0 = bx * 128, m0 = by * 128;
  int Kend = K;
  if (MODE == 4) Kend = min(K, m0 + 128);            // probs zero past diag

  const int lane = tid & 63;
  const int wm = (tid >> 6) >> 1, wn = (tid >> 6) & 1;
  const int l16 = lane & 15, kg = lane >> 4;
  const int srow = tid >> 2, scol = (tid & 3) * 8;   // staging: 64 rows x 32 cols /issue
  const int lbase = (tid & ~63) * 8;                 // wave-uniform LDS elem base

  f32x4 acc[4][4];
  #pragma unroll
  for (int a = 0; a < 4; a++)
    #pragma unroll
    for (int b = 0; b < 4; b++)
      #pragma unroll
      for (int j = 0; j < 4; j++) acc[a][b][j] = 0.f;

  for (int k0 = 0; k0 < Kend; k0 += 32) {
    #pragma unroll
    for (int i = 0; i < 2; i++) {
      const short* gp = Ap + (size_t)(m0 + i * 64 + srow) * lda + (k0 + scol);
      gload16(gp, &lA[i * 2048 + lbase]);
    }
    #pragma unroll
    for (int i = 0; i < 2; i++) {
      int gr = n0 + i * 64 + srow; gr = min(gr, N - 1);   // PV N=64 clamp
      const short* gp = Bp + (size_t)gr * ldb + (k0 + scol);
      gload16(gp, &lB[i * 2048 + lbase]);
    }
    __syncthreads();
    short8_t af[4], bf[4];
    #pragma unroll
    for (int mi = 0; mi < 4; mi++)
      af[mi] = *(const short8_t*)&lA[(wm * 64 + mi * 16 + l16) * 32 + kg * 8];
    #pragma unroll
    for (int ni = 0; ni < 4; ni++)
      bf[ni] = *(const short8_t*)&lB[(wn * 64 + ni * 16 + l16) * 32 + kg * 8];
    #pragma unroll
    for (int mi = 0; mi < 4; mi++)
      #pragma unroll
      for (int ni = 0; ni < 4; ni++)
        acc[mi][ni] = __builtin_amdgcn_mfma_f32_16x16x32_bf16(
            af[mi], bf[ni], acc[mi][ni], 0, 0, 0);
    __syncthreads();
  }

  #pragma unroll
  for (int mi = 0; mi < 4; mi++) {
    #pragma unroll
    for (int ni = 0; ni < 4; ni++) {
      #pragma unroll
      for (int j = 0; j < 4; j++) {
        const int r = m0 + wm * 64 + mi * 16 + kg * 4 + j;   // C/D row (m89)
        const int c = n0 + wn * 64 + ni * 16 + l16;          // C/D col
        const float v = acc[mi][ni][j];
        if (MODE == 4) {
          if (c < N) {
            int b = z >> 4, h = z & 15;
            ((short*)Cp)[((size_t)(b * SS + r)) * DD + h * HDD + c] = f2bf(v);
          }
        } else if (MODE == 5) {
          ((float*)Cp)[(size_t)r * N + c] = v;
        } else if (MODE == 6) {
          ((short*)Cp)[(size_t)r * N + c] = f2bf(fmaxf(v + bias[c], 0.f));
        } else if (MODE == 7 || MODE == 9) {
          ((float*)Cp)[(size_t)r * N + c] = v + bias[c];
        } else if (MODE == 8) {
          int kind = c >> 10, cc = c & 1023;
          int b = r >> 10, s = r & 1023, h = cc >> 6, hd = cc & 63;
          size_t off;
          if (kind < 2)
            off = (size_t)kind * MROWS * DD +
                  (((size_t)(b * HH + h) << 10) + s) * HDD + hd;
          else
            off = (size_t)2 * MROWS * DD +
                  (((size_t)(b * HH + h) * HDD + hd) << 10) + s;
          ((short*)Cp)[off] = f2bf(v);
        }
      }
    }
  }
}

// ------- fused scores+softmax: P = softmax(causal(Q K^T * 0.125)) as bf16 -------
// grid (8, B*H), 256 thr (4 waves); q-block 128 rows, k-tiles of 128.
// LDS tiles [128][64] bf16 with XOR swizzle byte^=((row&7)<<4) (rule #21:
// linear gload_lds dest + inverse-swizzled global source + swizzled read).
#define RDSWZ(arr, r, cb) \
  (*(const short8_t*)&arr[((r) << 6) + ((((cb) ^ (((r) & 7) << 4))) >> 1)])

__global__ __launch_bounds__(256) void k_qksm(
    const short* __restrict__ Q, const short* __restrict__ Kg,
    short* __restrict__ P) {
  __shared__ short lQ[8192];
  __shared__ short lK[8192];
  const int tid = threadIdx.x;
  const int qb = blockIdx.x, z = blockIdx.y;
  const int q0 = qb << 7;
  const short* Qp = Q + ((size_t)z << 16);    // [S][64] per (b,h)
  const short* Kp = Kg + ((size_t)z << 16);
  short* Pp = P + ((size_t)z << 20);
  const int lane = tid & 63, w = tid >> 6;
  const int l16 = lane & 15, kgp = lane >> 4;
  const int sr = tid >> 3;                    // staging row 0..31 per issue
  const int scb = ((tid & 7) << 4) ^ ((sr & 7) << 4);  // pre-swizzled src byte col
  const int ldst = (tid & ~63) << 3;          // wave-uniform dest elem base

  // stage Q once (stays resident)
  #pragma unroll
  for (int i = 0; i < 4; i++)
    gload16(Qp + ((size_t)(q0 + i * 32 + sr) << 6) + (scb >> 1),
            &lQ[i * 2048 + ldst]);

  float m_r[2][4], s_r[2][4];
  #pragma unroll
  for (int mi = 0; mi < 2; mi++)
    #pragma unroll
    for (int j = 0; j < 4; j++) { m_r[mi][j] = -3e38f; s_r[mi][j] = 0.f; }

  const int nkt = qb + 1;
  // ---- pass 1: online max/sum ----
  for (int kt = 0; kt < nkt; kt++) {
    const int k0 = kt << 7;
    #pragma unroll
    for (int i = 0; i < 4; i++)
      gload16(Kp + ((size_t)(k0 + i * 32 + sr) << 6) + (scb >> 1),
              &lK[i * 2048 + ldst]);
    __syncthreads();
    f32x4 acc[2][8];
    #pragma unroll
    for (int mi = 0; mi < 2; mi++)
      #pragma unroll
      for (int nf = 0; nf < 8; nf++)
        #pragma unroll
        for (int j = 0; j < 4; j++) acc[mi][nf][j] = 0.f;
    #pragma unroll
    for (int kk = 0; kk < 2; kk++) {
      short8_t aq[2];
      #pragma unroll
      for (int mi = 0; mi < 2; mi++)
        aq[mi] = RDSWZ(lQ, w * 32 + mi * 16 + l16, kk * 64 + kgp * 16);
      #pragma unroll
      for (int nf = 0; nf < 8; nf++) {
        short8_t bk = RDSWZ(lK, nf * 16 + l16, kk * 64 + kgp * 16);
        #pragma unroll
        for (int mi = 0; mi < 2; mi++)
          acc[mi][nf] = __builtin_amdgcn_mfma_f32_16x16x32_bf16(
              aq[mi], bk, acc[mi][nf], 0, 0, 0);
      }
    }
    #pragma unroll
    for (int mi = 0; mi < 2; mi++) {
      #pragma unroll
      for (int j = 0; j < 4; j++) {
        const int q = q0 + w * 32 + mi * 16 + kgp * 4 + j;
        float sv[8]; float tm = -3e38f;
        #pragma unroll
        for (int nf = 0; nf < 8; nf++) {
          int kv = k0 + nf * 16 + l16;
          sv[nf] = (kv <= q) ? acc[mi][nf][j] * 0.125f : -3e38f;
          tm = fmaxf(tm, sv[nf]);
        }
        #pragma unroll
        for (int o = 1; o < 16; o <<= 1) tm = fmaxf(tm, __shfl_xor(tm, o));
        float mn = fmaxf(m_r[mi][j], tm);
        float ts = 0.f;
        #pragma unroll
        for (int nf = 0; nf < 8; nf++) ts += __expf(sv[nf] - mn);
        #pragma unroll
        for (int o = 1; o < 16; o <<= 1) ts += __shfl_xor(ts, o);
        s_r[mi][j] = s_r[mi][j] * __expf(m_r[mi][j] - mn) + ts;
        m_r[mi][j] = mn;
      }
    }
    __syncthreads();
  }

  float inv[2][4];
  #pragma unroll
  for (int mi = 0; mi < 2; mi++)
    #pragma unroll
    for (int j = 0; j < 4; j++) inv[mi][j] = 1.f / s_r[mi][j];

  // ---- pass 2: recompute, normalize, write bf16 probs ----
  for (int kt = 0; kt < nkt; kt++) {
    const int k0 = kt << 7;
    #pragma unroll
    for (int i = 0; i < 4; i++)
      gload16(Kp + ((size_t)(k0 + i * 32 + sr) << 6) + (scb >> 1),
              &lK[i * 2048 + ldst]);
    __syncthreads();
    f32x4 acc[2][8];
    #pragma unroll
    for (int mi = 0; mi < 2; mi++)
      #pragma unroll
      for (int nf = 0; nf < 8; nf++)
        #pragma unroll
        for (int j = 0; j < 4; j++) acc[mi][nf][j] = 0.f;
    #pragma unroll
    for (int kk = 0; kk < 2; kk++) {
      short8_t aq[2];
      #pragma unroll
      for (int mi = 0; mi < 2; mi++)
        aq[mi] = RDSWZ(lQ, w * 32 + mi * 16 + l16, kk * 64 + kgp * 16);
      #pragma unroll
      for (int nf = 0; nf < 8; nf++) {
        short8_t bk = RDSWZ(lK, nf * 16 + l16, kk * 64 + kgp * 16);
        #pragma unroll
        for (int mi = 0; mi < 2; mi++)
          acc[mi][nf] = __builtin_amdgcn_mfma_f32_16x16x32_bf16(
              aq[mi], bk, acc[mi][nf], 0, 0, 0);
      }
    }
    #pragma unroll
    for (int mi = 0; mi < 2; mi++) {
      #pragma unroll
      for (int j = 0; j < 4; j++) {
        const int q = q0 + w * 32 + mi * 16 + kgp * 4 + j;
        #pragma unroll
        for (int nf = 0; nf < 8; nf++) {
          int kv = k0 + nf * 16 + l16;
          float p = (kv <= q)
              ? __expf(acc[mi][nf][j] * 0.125f - m_r[mi][j]) * inv[mi][j]
              : 0.f;
          Pp[((size_t)q << 10) + kv] = f2bf(p);
        }
      }
    }
    __syncthreads();
  }
}

// ---------------- LayerNorm (D=1024) with optional residual ----------------
template<int ADD_RES, int WRITE_F32>
__global__ __launch_bounds__(256) void k_ln(
    const float* __restrict__ src, const float* __restrict__ res,
    const float* __restrict__ g, const float* __restrict__ b,
    float* __restrict__ of, short* __restrict__ ob) {
  const int row = blockIdx.x;
  const int tid = threadIdx.x;
  float4 v = ((const float4*)(src + ((size_t)row << 10)))[tid];
  float s1 = v.x + v.y + v.z + v.w;
  float s2 = v.x * v.x + v.y * v.y + v.z * v.z + v.w * v.w;
  #pragma unroll
  for (int o = 32; o; o >>= 1) { s1 += __shfl_xor(s1, o); s2 += __shfl_xor(s2, o); }
  __shared__ float sh1[4], sh2[4];
  if ((tid & 63) == 0) { sh1[tid >> 6] = s1; sh2[tid >> 6] = s2; }
  __syncthreads();
  s1 = sh1[0] + sh1[1] + sh1[2] + sh1[3];
  s2 = sh2[0] + sh2[1] + sh2[2] + sh2[3];
  const float mean = s1 * (1.f / 1024.f);
  const float var  = s2 * (1.f / 1024.f) - mean * mean;
  const float rs = rsqrtf(var + 1e-5f);
  float4 gg = ((const float4*)g)[tid];
  float4 bb = ((const float4*)b)[tid];
  float4 o4;
  o4.x = (v.x - mean) * rs * gg.x + bb.x;
  o4.y = (v.y - mean) * rs * gg.y + bb.y;
  o4.z = (v.z - mean) * rs * gg.z + bb.z;
  o4.w = (v.w - mean) * rs * gg.w + bb.w;
  if (ADD_RES) {
    float4 rr = ((const float4*)(res + ((size_t)row << 10)))[tid];
    o4.x += rr.x; o4.y += rr.y; o4.z += rr.z; o4.w += rr.w;
  }
  if (WRITE_F32) ((float4*)(of + ((size_t)row << 10)))[tid] = o4;
  short4 s4; s4.x = f2bf(o4.x); s4.y = f2bf(o4.y);
  s4.z = f2bf(o4.z); s4.w = f2bf(o4.w);
  ((short4*)ob)[((size_t)row << 8) + tid] = s4;
}

extern "C" void kernel_launch(void* const* d_in, const int* in_sizes, int n_in,
                              void* d_out, int out_size, void* d_ws, size_t ws_size,
                              hipStream_t stream) {
  (void)in_sizes; (void)n_in; (void)out_size; (void)ws_size;
  const int*   tokens  = (const int*)d_in[0];
  const float* tok_emb = (const float*)d_in[1];
  const float* pos_emb = (const float*)d_in[2];
  const float* Wq = (const float*)d_in[3];
  const float* Wk = (const float*)d_in[4];
  const float* Wv = (const float*)d_in[5];
  const float* Wp = (const float*)d_in[6];
  const float* ln1s = (const float*)d_in[7];
  const float* ln1b = (const float*)d_in[8];
  const float* W1 = (const float*)d_in[9];
  const float* b1 = (const float*)d_in[10];
  const float* W2 = (const float*)d_in[11];
  const float* b2 = (const float*)d_in[12];
  const float* ln2s = (const float*)d_in[13];
  const float* ln2b = (const float*)d_in[14];
  const float* lnfs = (const float*)d_in[15];
  const float* lnfb = (const float*)d_in[16];
  const float* Wh = (const float*)d_in[17];
  const float* bh = (const float*)d_in[18];
  float* out = (float*)d_out;

  char* p = (char*)d_ws;
  auto alloc = [&](size_t elems, size_t esz) -> char* {
    char* r = p; p += (elems * esz + 255) & ~(size_t)255; return r;
  };
  short* WqkvT = (short*)alloc((size_t)LNUM * 3 * DD * DD, 2);  // [L][3][D][D]
  short* WpT = (short*)alloc((size_t)LNUM * DD * DD, 2);
  short* W1T = (short*)alloc((size_t)LNUM * DD * FF, 2);
  short* W2T = (short*)alloc((size_t)LNUM * DD * FF, 2);
  short* WhT = (short*)alloc((size_t)DD * VV, 2);
  float* xf   = (float*)alloc((size_t)MROWS * DD, 4);   // fp32 residual stream
  float* ff   = (float*)alloc((size_t)MROWS * DD, 4);
  short* xb   = (short*)alloc((size_t)MROWS * DD, 2);
  short* ab   = (short*)alloc((size_t)MROWS * DD, 2);
  short* qkvb = (short*)alloc((size_t)3 * MROWS * DD, 2); // q | k | v^T contiguous
  short* obuf = (short*)alloc((size_t)MROWS * DD, 2);
  short* hb   = (short*)alloc((size_t)MROWS * FF, 2);
  short* xfb  = (short*)alloc((size_t)MROWS * DD, 2);
  short* prob = (short*)alloc((size_t)BB * HH * SS * SS, 2);
  short* qb   = qkvb;
  short* kb   = qkvb + (size_t)MROWS * DD;
  short* vtb  = qkvb + (size_t)2 * MROWS * DD;

  dim3 blk(256);
  dim3 t8(32, 8);
  const long long DD2 = (long long)DD * DD;
  // weight convert+transpose (per call; deterministic)
  k_tcvt<<<dim3(DD / 32, DD / 32, LNUM), t8, 0, stream>>>(Wq, WqkvT,          DD, DD, 3 * DD2);
  k_tcvt<<<dim3(DD / 32, DD / 32, LNUM), t8, 0, stream>>>(Wk, WqkvT + DD2,    DD, DD, 3 * DD2);
  k_tcvt<<<dim3(DD / 32, DD / 32, LNUM), t8, 0, stream>>>(Wv, WqkvT + 2*DD2,  DD, DD, 3 * DD2);
  k_tcvt<<<dim3(DD / 32, DD / 32, LNUM), t8, 0, stream>>>(Wp, WpT, DD, DD, DD2);
  k_tcvt<<<dim3(FF / 32, DD / 32, LNUM), t8, 0, stream>>>(W1, W1T, DD, FF, (long long)DD * FF);
  k_tcvt<<<dim3(DD / 32, FF / 32, LNUM), t8, 0, stream>>>(W2, W2T, FF, DD, (long long)DD * FF);
  k_tcvt<<<dim3(VV / 32, DD / 32, 1),   t8, 0, stream>>>(Wh, WhT, DD, VV, 0);

  k_embed<<<(MROWS * DD / 4) / 256, blk, 0, stream>>>(tokens, tok_emb, pos_emb, xf, xb);

  for (int l = 0; l < LNUM; l++) {
    const short* wqkv = WqkvT + (size_t)l * 3 * DD * DD;
    const short* wp = WpT + (size_t)l * DD * DD;
    const short* w1 = W1T + (size_t)l * DD * FF;
    const short* w2 = W2T + (size_t)l * DD * FF;

    // fused QKV projection: [4096 x 3072]
    k_gemm<8><<<dim3(24, 32, 1), blk, 0, stream>>>(xb, wqkv, nullptr, qkvb,
        MROWS, 3 * DD, DD, DD, DD, 0, 0);
    // fused scores+softmax -> bf16 probs
    k_qksm<<<dim3(8, BB * HH), blk, 0, stream>>>(qb, kb, prob);
    // o[b,h] = P @ V   (A=probs [S,S], Bt=v^T [HD,S])
    k_gemm<4><<<dim3(1, 8, BB * HH), blk, 0, stream>>>(prob, vtb, nullptr, obuf,
        SS, HDD, SS, SS, SS, (long long)SS * SS, (long long)HDD * SS);
    // proj
    k_gemm<5><<<dim3(8, 32, 1), blk, 0, stream>>>(obuf, wp, nullptr, ff,
        MROWS, DD, DD, DD, DD, 0, 0);
    k_ln<1, 0><<<MROWS, blk, 0, stream>>>(ff, xf, ln1s + (size_t)l * DD,
        ln1b + (size_t)l * DD, nullptr, ab);
    // ffn
    k_gemm<6><<<dim3(32, 32, 1), blk, 0, stream>>>(ab, w1, b1 + (size_t)l * FF, hb,
        MROWS, FF, DD, DD, DD, 0, 0);
    k_gemm<7><<<dim3(8, 32, 1), blk, 0, stream>>>(hb, w2, b2 + (size_t)l * DD, ff,
        MROWS, DD, FF, FF, FF, 0, 0);
    k_ln<1, 1><<<MROWS, blk, 0, stream>>>(ff, xf, ln2s + (size_t)l * DD,
        ln2b + (size_t)l * DD, xf, xb);
  }

  k_ln<0, 0><<<MROWS, blk, 0, stream>>>(xf, nullptr, lnfs, lnfb, nullptr, xfb);
  // logits = lnf(x) @ Wh + bh   (XCD-swizzled: 8000 blocks % 8 == 0)
  k_gemm<9><<<dim3(VV / 128, 32, 1), blk, 0, stream>>>(xfb, WhT, bh, out,
      MROWS, VV, DD, DD, DD, 0, 0);
}

// Round 3
// 2803.925 us; speedup vs baseline: 1.2880x; 1.0260x over previous
//
#include <hip/hip_runtime.h>

#define DEV __device__ __forceinline__

typedef __attribute__((ext_vector_type(4))) float f32x4;
typedef __attribute__((ext_vector_type(8))) short short8_t;

constexpr int LNUM = 6;
constexpr int BB = 4;
constexpr int SS = 1024;
constexpr int DD = 1024;
constexpr int HH = 16;
constexpr int HDD = 64;
constexpr int FF = 4096;
constexpr int VV = 32000;
constexpr int MROWS = BB * SS;   // 4096

DEV short f2bf(float f) {
  union { float f; unsigned u; } x; x.f = f;
  unsigned r = x.u + 0x7fffu + ((x.u >> 16) & 1u);   // RNE
  return (short)(r >> 16);
}

#define BAR() do { __builtin_amdgcn_sched_barrier(0); \
  __builtin_amdgcn_s_barrier(); \
  __builtin_amdgcn_sched_barrier(0); } while (0)

// ---------------- embedding: x = tok_emb[tok] + pos_emb ----------------
__global__ __launch_bounds__(256) void k_embed(
    const int* __restrict__ tok, const float* __restrict__ te,
    const float* __restrict__ pe, float* __restrict__ xf,
    short* __restrict__ xb) {
  int i = blockIdx.x * 256 + threadIdx.x;            // over MROWS*DD/4
  int bs = i >> 8, d4 = i & 255;
  int t = tok[bs];
  float4 a = ((const float4*)(te + (size_t)t * DD))[d4];
  float4 b = ((const float4*)(pe + (size_t)(bs & (SS - 1)) * DD))[d4];
  float4 r; r.x = a.x + b.x; r.y = a.y + b.y; r.z = a.z + b.z; r.w = a.w + b.w;
  ((float4*)xf)[i] = r;
  short4 o; o.x = f2bf(r.x); o.y = f2bf(r.y); o.z = f2bf(r.z); o.w = f2bf(r.w);
  ((short4*)xb)[i] = o;
}

// ------- transpose + fp32->bf16: W[K,N] -> Wt[N,K] bf16, out stride per z -------
__global__ __launch_bounds__(256) void k_tcvt(
    const float* __restrict__ in, short* __restrict__ out, int K, int N,
    long long ostride) {
  __shared__ float tile[32][33];
  const float* ip = in + (size_t)blockIdx.z * K * N;
  short* op = out + (size_t)blockIdx.z * ostride;
  int bn = blockIdx.x * 32, bk = blockIdx.y * 32;
  int tx = threadIdx.x, ty = threadIdx.y;            // (32,8)
  #pragma unroll
  for (int r = 0; r < 32; r += 8)
    tile[ty + r][tx] = ip[(size_t)(bk + ty + r) * N + bn + tx];
  __syncthreads();
  #pragma unroll
  for (int r = 0; r < 32; r += 8)
    op[(size_t)(bn + ty + r) * K + bk + tx] = f2bf(tile[tx][ty + r]);
}

DEV void gload16(const short* g, short* l) {
  __builtin_amdgcn_global_load_lds(
      (const __attribute__((address_space(1))) void*)g,
      (__attribute__((address_space(3))) void*)l, 16, 0, 0);
}

// ============ 256x256 8-phase bf16 GEMM (T2+T3+T4+T5), BK=64 ============
// A[M,K] bf16 row-major, Bt[N,K] bf16 row-major. 512 thr = 8 waves (2M x 4N).
// Per-wave out 128x64 = acc[8][4] 16x16 frags. LDS 128 KiB dynamic:
// [buf][A 256x64 | B 256x64], halves of 128 rows. Swizzle: byte^=((row&7)<<4)
// applied on BOTH stage-source and ds_read (rule #21). Counted vmcnt(8) once
// per K-tile window; stages: P2=B(t+2), P3=A(t+2) into just-freed slots.
// MODEs: 6 relu+bias->bf16; 8 fused QKV; 9 fp32+bias (logits).
// Requires M%256==0, N%256==0, K%64==0, K/64>=2, gridDim.y==16, nwg%8==0.
template<int MODE>
__global__ __launch_bounds__(512, 2) void k_gemm256(
    const short* __restrict__ A, const short* __restrict__ Bt,
    const float* __restrict__ bias, void* __restrict__ Cp,
    int M, int N, int K, int lda, int ldb) {
  extern __shared__ short lds[];
  const int tid = threadIdx.x;
  // XCD-bijective swizzle, N-major chunks (full-M per XCD chunk -> L2 reuse)
  const int nbx = gridDim.x;
  const int nwg = nbx << 4;
  const int hid = blockIdx.y * nbx + blockIdx.x;
  const int cpx = nwg >> 3;
  const int lid = (hid & 7) * cpx + (hid >> 3);
  const int bx = lid >> 4, by = lid & 15;
  const int n0 = bx * 256, m0 = by * 256;

  const int lane = tid & 63;
  const int wid = tid >> 6;
  const int wm = wid >> 2, wn = wid & 3;
  const int l16 = lane & 15, kg = lane >> 4;
  const int xorv = (l16 & 7) << 4;                    // byte-col XOR for reads
  const int cs[2] = { ((kg << 4) ^ xorv) >> 1,
                      ((64 | (kg << 4)) ^ xorv) >> 1 };
  // staging geometry: one gload16 issue covers 64 rows x 64 cols (8 thr/row)
  const int rr = tid >> 3;                            // 0..63
  const int sce = ((((tid & 7) << 4) ^ ((rr & 7) << 4)) >> 1);
  const int ldst = (tid & ~63) * 8;                   // wave-uniform elem base

  const int NT = K >> 6;

  auto stageA = [&](int t2, int c2) {
    const int k0 = t2 << 6;
    const int base = c2 * 32768;
    #pragma unroll
    for (int h = 0; h < 2; h++)
      #pragma unroll
      for (int li = 0; li < 2; li++)
        gload16(A + (size_t)(m0 + h * 128 + li * 64 + rr) * lda + k0 + sce,
                &lds[base + h * 8192 + li * 4096 + ldst]);
  };
  auto stageB = [&](int t2, int c2) {
    const int k0 = t2 << 6;
    const int base = c2 * 32768 + 16384;
    #pragma unroll
    for (int h = 0; h < 2; h++)
      #pragma unroll
      for (int li = 0; li < 2; li++)
        gload16(Bt + (size_t)(n0 + h * 128 + li * 64 + rr) * ldb + k0 + sce,
                &lds[base + h * 8192 + li * 4096 + ldst]);
  };

  f32x4 acc[8][4];
  #pragma unroll
  for (int mi = 0; mi < 8; mi++)
    #pragma unroll
    for (int ni = 0; ni < 4; ni++)
      #pragma unroll
      for (int j = 0; j < 4; j++) acc[mi][ni][j] = 0.f;

  // prologue: tile0 -> buf0, tile1 -> buf1; wait tile0 landed (8 newest allowed)
  stageA(0, 0); stageB(0, 0);
  stageA(1, 1); stageB(1, 1);
  asm volatile("s_waitcnt vmcnt(8)" ::: "memory");
  BAR();

  for (int t = 0; t < NT; t++) {
    const int c = t & 1;
    const int ao = c * 32768 + wm * 8192;
    const int bo = c * 32768 + 16384 + (wn >> 1) * 8192 + (wn & 1) * 4096;
    short8_t a[4][2], b0[2][2], b1[2][2];

    // ---- P0: read a_lo (8) + b0 (4); MFMA (lo x n0-1) ----
    #pragma unroll
    for (int mi = 0; mi < 4; mi++)
      #pragma unroll
      for (int kk = 0; kk < 2; kk++)
        a[mi][kk] = *(const short8_t*)&lds[ao + (mi * 16 + l16) * 64 + cs[kk]];
    #pragma unroll
    for (int ni = 0; ni < 2; ni++)
      #pragma unroll
      for (int kk = 0; kk < 2; kk++)
        b0[ni][kk] = *(const short8_t*)&lds[bo + (ni * 16 + l16) * 64 + cs[kk]];
    BAR();
    __builtin_amdgcn_s_setprio(1);
    #pragma unroll
    for (int mi = 0; mi < 4; mi++)
      #pragma unroll
      for (int ni = 0; ni < 2; ni++)
        #pragma unroll
        for (int kk = 0; kk < 2; kk++)
          acc[mi][ni] = __builtin_amdgcn_mfma_f32_16x16x32_bf16(
              a[mi][kk], b0[ni][kk], acc[mi][ni], 0, 0, 0);
    __builtin_amdgcn_s_setprio(0);
    BAR();

    // ---- P1: read b1 (4); MFMA (lo x n2-3) ----
    #pragma unroll
    for (int ni = 0; ni < 2; ni++)
      #pragma unroll
      for (int kk = 0; kk < 2; kk++)
        b1[ni][kk] = *(const short8_t*)&lds[bo + ((ni + 2) * 16 + l16) * 64 + cs[kk]];
    BAR();
    __builtin_amdgcn_s_setprio(1);
    #pragma unroll
    for (int mi = 0; mi < 4; mi++)
      #pragma unroll
      for (int ni = 0; ni < 2; ni++)
        #pragma unroll
        for (int kk = 0; kk < 2; kk++)
          acc[mi][ni + 2] = __builtin_amdgcn_mfma_f32_16x16x32_bf16(
              a[mi][kk], b1[ni][kk], acc[mi][ni + 2], 0, 0, 0);
    __builtin_amdgcn_s_setprio(0);
    BAR();                 // B slots of buf c now fully consumed by all waves

    // ---- P2: read a_hi (8); stage B(t+2)->buf c; MFMA (hi x n2-3) ----
    #pragma unroll
    for (int mi = 0; mi < 4; mi++)
      #pragma unroll
      for (int kk = 0; kk < 2; kk++)
        a[mi][kk] = *(const short8_t*)&lds[ao + ((mi + 4) * 16 + l16) * 64 + cs[kk]];
    if (t + 2 < NT) stageB(t + 2, c);
    BAR();
    __builtin_amdgcn_s_setprio(1);
    #pragma unroll
    for (int mi = 0; mi < 4; mi++)
      #pragma unroll
      for (int ni = 0; ni < 2; ni++)
        #pragma unroll
        for (int kk = 0; kk < 2; kk++)
          acc[mi + 4][ni + 2] = __builtin_amdgcn_mfma_f32_16x16x32_bf16(
              a[mi][kk], b1[ni][kk], acc[mi + 4][ni + 2], 0, 0, 0);
    __builtin_amdgcn_s_setprio(0);
    BAR();                 // A slots of buf c now fully consumed

    // ---- P3: stage A(t+2)->buf c; MFMA (hi x n0-1); counted vmcnt ----
    if (t + 2 < NT) stageA(t + 2, c);
    BAR();
    __builtin_amdgcn_s_setprio(1);
    #pragma unroll
    for (int mi = 0; mi < 4; mi++)
      #pragma unroll
      for (int ni = 0; ni < 2; ni++)
        #pragma unroll
        for (int kk = 0; kk < 2; kk++)
          acc[mi + 4][ni] = __builtin_amdgcn_mfma_f32_16x16x32_bf16(
              a[mi][kk], b0[ni][kk], acc[mi + 4][ni], 0, 0, 0);
    __builtin_amdgcn_s_setprio(0);
    if (t + 2 < NT) asm volatile("s_waitcnt vmcnt(8)" ::: "memory");
    else            asm volatile("s_waitcnt vmcnt(0)" ::: "memory");
    BAR();                 // next window may read buf ~c
  }

  // ---- epilogue ----
  #pragma unroll
  for (int mi = 0; mi < 8; mi++) {
    #pragma unroll
    for (int ni = 0; ni < 4; ni++) {
      #pragma unroll
      for (int j = 0; j < 4; j++) {
        const int r = m0 + wm * 128 + mi * 16 + kg * 4 + j;
        const int c = n0 + wn * 64 + ni * 16 + l16;
        const float v = acc[mi][ni][j];
        if (MODE == 6) {
          ((short*)Cp)[(size_t)r * N + c] = f2bf(fmaxf(v + bias[c], 0.f));
        } else if (MODE == 9) {
          ((float*)Cp)[(size_t)r * N + c] = v + bias[c];
        } else if (MODE == 8) {
          int kind = c >> 10, cc = c & 1023;
          int b = r >> 10, s = r & 1023, h = cc >> 6, hd = cc & 63;
          size_t off;
          if (kind < 2)
            off = (size_t)kind * MROWS * DD +
                  (((size_t)(b * HH + h) << 10) + s) * HDD + hd;
          else
            off = (size_t)2 * MROWS * DD +
                  (((size_t)(b * HH + h) * HDD + hd) << 10) + s;
          ((short*)Cp)[off] = f2bf(v);
        }
      }
    }
  }
}

// ---------------- bf16 MFMA GEMM, 128x128 tile, BK=32 (small-N shapes) ----------------
// MODEs: 4 PV out; 5 fp32; 7 fp32 x+bias
template<int MODE>
__global__ __launch_bounds__(256) void k_gemm(
    const short* __restrict__ A, const short* __restrict__ Bt,
    const float* __restrict__ bias, void* __restrict__ Cp,
    int M, int N, int K, int lda, int ldb,
    long long bsA, long long bsB) {
  __shared__ short lA[4096];
  __shared__ short lB[4096];
  const int tid = threadIdx.x;
  const int z = blockIdx.z;
  const short* Ap = A + (size_t)z * bsA;
  const short* Bp = Bt + (size_t)z * bsB;
  const int n0 = blockIdx.x * 128, m0 = blockIdx.y * 128;
  int Kend = K;
  if (MODE == 4) Kend = min(K, m0 + 128);            // probs zero past diag

  const int lane = tid & 63;
  const int wm = (tid >> 6) >> 1, wn = (tid >> 6) & 1;
  const int l16 = lane & 15, kg = lane >> 4;
  const int srow = tid >> 2, scol = (tid & 3) * 8;
  const int lbase = (tid & ~63) * 8;

  f32x4 acc[4][4];
  #pragma unroll
  for (int a = 0; a < 4; a++)
    #pragma unroll
    for (int b = 0; b < 4; b++)
      #pragma unroll
      for (int j = 0; j < 4; j++) acc[a][b][j] = 0.f;

  for (int k0 = 0; k0 < Kend; k0 += 32) {
    #pragma unroll
    for (int i = 0; i < 2; i++) {
      const short* gp = Ap + (size_t)(m0 + i * 64 + srow) * lda + (k0 + scol);
      gload16(gp, &lA[i * 2048 + lbase]);
    }
    #pragma unroll
    for (int i = 0; i < 2; i++) {
      int gr = n0 + i * 64 + srow; gr = min(gr, N - 1);   // PV N=64 clamp
      const short* gp = Bp + (size_t)gr * ldb + (k0 + scol);
      gload16(gp, &lB[i * 2048 + lbase]);
    }
    __syncthreads();
    short8_t af[4], bf[4];
    #pragma unroll
    for (int mi = 0; mi < 4; mi++)
      af[mi] = *(const short8_t*)&lA[(wm * 64 + mi * 16 + l16) * 32 + kg * 8];
    #pragma unroll
    for (int ni = 0; ni < 4; ni++)
      bf[ni] = *(const short8_t*)&lB[(wn * 64 + ni * 16 + l16) * 32 + kg * 8];
    #pragma unroll
    for (int mi = 0; mi < 4; mi++)
      #pragma unroll
      for (int ni = 0; ni < 4; ni++)
        acc[mi][ni] = __builtin_amdgcn_mfma_f32_16x16x32_bf16(
            af[mi], bf[ni], acc[mi][ni], 0, 0, 0);
    __syncthreads();
  }

  #pragma unroll
  for (int mi = 0; mi < 4; mi++) {
    #pragma unroll
    for (int ni = 0; ni < 4; ni++) {
      #pragma unroll
      for (int j = 0; j < 4; j++) {
        const int r = m0 + wm * 64 + mi * 16 + kg * 4 + j;
        const int c = n0 + wn * 64 + ni * 16 + l16;
        const float v = acc[mi][ni][j];
        if (MODE == 4) {
          if (c < N) {
            int b = z >> 4, h = z & 15;
            ((short*)Cp)[((size_t)(b * SS + r)) * DD + h * HDD + c] = f2bf(v);
          }
        } else if (MODE == 5) {
          ((float*)Cp)[(size_t)r * N + c] = v;
        } else if (MODE == 7) {
          ((float*)Cp)[(size_t)r * N + c] = v + bias[c];
        }
      }
    }
  }
}

// ------- fused scores+softmax: P = softmax(causal(Q K^T * 0.125)) as bf16 -------
#define RDSWZ(arr, r, cb) \
  (*(const short8_t*)&arr[((r) << 6) + ((((cb) ^ (((r) & 7) << 4))) >> 1)])

__global__ __launch_bounds__(256) void k_qksm(
    const short* __restrict__ Q, const short* __restrict__ Kg,
    short* __restrict__ P) {
  __shared__ short lQ[8192];
  __shared__ short lK[8192];
  const int tid = threadIdx.x;
  const int qb = blockIdx.x, z = blockIdx.y;
  const int q0 = qb << 7;
  const short* Qp = Q + ((size_t)z << 16);    // [S][64] per (b,h)
  const short* Kp = Kg + ((size_t)z << 16);
  short* Pp = P + ((size_t)z << 20);
  const int lane = tid & 63, w = tid >> 6;
  const int l16 = lane & 15, kgp = lane >> 4;
  const int sr = tid >> 3;
  const int scb = ((tid & 7) << 4) ^ ((sr & 7) << 4);
  const int ldst = (tid & ~63) << 3;

  #pragma unroll
  for (int i = 0; i < 4; i++)
    gload16(Qp + ((size_t)(q0 + i * 32 + sr) << 6) + (scb >> 1),
            &lQ[i * 2048 + ldst]);

  float m_r[2][4], s_r[2][4];
  #pragma unroll
  for (int mi = 0; mi < 2; mi++)
    #pragma unroll
    for (int j = 0; j < 4; j++) { m_r[mi][j] = -3e38f; s_r[mi][j] = 0.f; }

  const int nkt = qb + 1;
  for (int kt = 0; kt < nkt; kt++) {
    const int k0 = kt << 7;
    #pragma unroll
    for (int i = 0; i < 4; i++)
      gload16(Kp + ((size_t)(k0 + i * 32 + sr) << 6) + (scb >> 1),
              &lK[i * 2048 + ldst]);
    __syncthreads();
    f32x4 acc[2][8];
    #pragma unroll
    for (int mi = 0; mi < 2; mi++)
      #pragma unroll
      for (int nf = 0; nf < 8; nf++)
        #pragma unroll
        for (int j = 0; j < 4; j++) acc[mi][nf][j] = 0.f;
    #pragma unroll
    for (int kk = 0; kk < 2; kk++) {
      short8_t aq[2];
      #pragma unroll
      for (int mi = 0; mi < 2; mi++)
        aq[mi] = RDSWZ(lQ, w * 32 + mi * 16 + l16, kk * 64 + kgp * 16);
      #pragma unroll
      for (int nf = 0; nf < 8; nf++) {
        short8_t bk = RDSWZ(lK, nf * 16 + l16, kk * 64 + kgp * 16);
        #pragma unroll
        for (int mi = 0; mi < 2; mi++)
          acc[mi][nf] = __builtin_amdgcn_mfma_f32_16x16x32_bf16(
              aq[mi], bk, acc[mi][nf], 0, 0, 0);
      }
    }
    #pragma unroll
    for (int mi = 0; mi < 2; mi++) {
      #pragma unroll
      for (int j = 0; j < 4; j++) {
        const int q = q0 + w * 32 + mi * 16 + kgp * 4 + j;
        float sv[8]; float tm = -3e38f;
        #pragma unroll
        for (int nf = 0; nf < 8; nf++) {
          int kv = k0 + nf * 16 + l16;
          sv[nf] = (kv <= q) ? acc[mi][nf][j] * 0.125f : -3e38f;
          tm = fmaxf(tm, sv[nf]);
        }
        #pragma unroll
        for (int o = 1; o < 16; o <<= 1) tm = fmaxf(tm, __shfl_xor(tm, o));
        float mn = fmaxf(m_r[mi][j], tm);
        float ts = 0.f;
        #pragma unroll
        for (int nf = 0; nf < 8; nf++) ts += __expf(sv[nf] - mn);
        #pragma unroll
        for (int o = 1; o < 16; o <<= 1) ts += __shfl_xor(ts, o);
        s_r[mi][j] = s_r[mi][j] * __expf(m_r[mi][j] - mn) + ts;
        m_r[mi][j] = mn;
      }
    }
    __syncthreads();
  }

  float inv[2][4];
  #pragma unroll
  for (int mi = 0; mi < 2; mi++)
    #pragma unroll
    for (int j = 0; j < 4; j++) inv[mi][j] = 1.f / s_r[mi][j];

  for (int kt = 0; kt < nkt; kt++) {
    const int k0 = kt << 7;
    #pragma unroll
    for (int i = 0; i < 4; i++)
      gload16(Kp + ((size_t)(k0 + i * 32 + sr) << 6) + (scb >> 1),
              &lK[i * 2048 + ldst]);
    __syncthreads();
    f32x4 acc[2][8];
    #pragma unroll
    for (int mi = 0; mi < 2; mi++)
      #pragma unroll
      for (int nf = 0; nf < 8; nf++)
        #pragma unroll
        for (int j = 0; j < 4; j++) acc[mi][nf][j] = 0.f;
    #pragma unroll
    for (int kk = 0; kk < 2; kk++) {
      short8_t aq[2];
      #pragma unroll
      for (int mi = 0; mi < 2; mi++)
        aq[mi] = RDSWZ(lQ, w * 32 + mi * 16 + l16, kk * 64 + kgp * 16);
      #pragma unroll
      for (int nf = 0; nf < 8; nf++) {
        short8_t bk = RDSWZ(lK, nf * 16 + l16, kk * 64 + kgp * 16);
        #pragma unroll
        for (int mi = 0; mi < 2; mi++)
          acc[mi][nf] = __builtin_amdgcn_mfma_f32_16x16x32_bf16(
              aq[mi], bk, acc[mi][nf], 0, 0, 0);
      }
    }
    #pragma unroll
    for (int mi = 0; mi < 2; mi++) {
      #pragma unroll
      for (int j = 0; j < 4; j++) {
        const int q = q0 + w * 32 + mi * 16 + kgp * 4 + j;
        #pragma unroll
        for (int nf = 0; nf < 8; nf++) {
          int kv = k0 + nf * 16 + l16;
          float p = (kv <= q)
              ? __expf(acc[mi][nf][j] * 0.125f - m_r[mi][j]) * inv[mi][j]
              : 0.f;
          Pp[((size_t)q << 10) + kv] = f2bf(p);
        }
      }
    }
    __syncthreads();
  }
}

// ---------------- LayerNorm (D=1024) with optional residual ----------------
template<int ADD_RES, int WRITE_F32>
__global__ __launch_bounds__(256) void k_ln(
    const float* __restrict__ src, const float* __restrict__ res,
    const float* __restrict__ g, const float* __restrict__ b,
    float* __restrict__ of, short* __restrict__ ob) {
  const int row = blockIdx.x;
  const int tid = threadIdx.x;
  float4 v = ((const float4*)(src + ((size_t)row << 10)))[tid];
  float s1 = v.x + v.y + v.z + v.w;
  float s2 = v.x * v.x + v.y * v.y + v.z * v.z + v.w * v.w;
  #pragma unroll
  for (int o = 32; o; o >>= 1) { s1 += __shfl_xor(s1, o); s2 += __shfl_xor(s2, o); }
  __shared__ float sh1[4], sh2[4];
  if ((tid & 63) == 0) { sh1[tid >> 6] = s1; sh2[tid >> 6] = s2; }
  __syncthreads();
  s1 = sh1[0] + sh1[1] + sh1[2] + sh1[3];
  s2 = sh2[0] + sh2[1] + sh2[2] + sh2[3];
  const float mean = s1 * (1.f / 1024.f);
  const float var  = s2 * (1.f / 1024.f) - mean * mean;
  const float rs = rsqrtf(var + 1e-5f);
  float4 gg = ((const float4*)g)[tid];
  float4 bb = ((const float4*)b)[tid];
  float4 o4;
  o4.x = (v.x - mean) * rs * gg.x + bb.x;
  o4.y = (v.y - mean) * rs * gg.y + bb.y;
  o4.z = (v.z - mean) * rs * gg.z + bb.z;
  o4.w = (v.w - mean) * rs * gg.w + bb.w;
  if (ADD_RES) {
    float4 rr = ((const float4*)(res + ((size_t)row << 10)))[tid];
    o4.x += rr.x; o4.y += rr.y; o4.z += rr.z; o4.w += rr.w;
  }
  if (WRITE_F32) ((float4*)(of + ((size_t)row << 10)))[tid] = o4;
  short4 s4; s4.x = f2bf(o4.x); s4.y = f2bf(o4.y);
  s4.z = f2bf(o4.z); s4.w = f2bf(o4.w);
  ((short4*)ob)[((size_t)row << 8) + tid] = s4;
}

extern "C" void kernel_launch(void* const* d_in, const int* in_sizes, int n_in,
                              void* d_out, int out_size, void* d_ws, size_t ws_size,
                              hipStream_t stream) {
  (void)in_sizes; (void)n_in; (void)out_size; (void)ws_size;
  const int*   tokens  = (const int*)d_in[0];
  const float* tok_emb = (const float*)d_in[1];
  const float* pos_emb = (const float*)d_in[2];
  const float* Wq = (const float*)d_in[3];
  const float* Wk = (const float*)d_in[4];
  const float* Wv = (const float*)d_in[5];
  const float* Wp = (const float*)d_in[6];
  const float* ln1s = (const float*)d_in[7];
  const float* ln1b = (const float*)d_in[8];
  const float* W1 = (const float*)d_in[9];
  const float* b1 = (const float*)d_in[10];
  const float* W2 = (const float*)d_in[11];
  const float* b2 = (const float*)d_in[12];
  const float* ln2s = (const float*)d_in[13];
  const float* ln2b = (const float*)d_in[14];
  const float* lnfs = (const float*)d_in[15];
  const float* lnfb = (const float*)d_in[16];
  const float* Wh = (const float*)d_in[17];
  const float* bh = (const float*)d_in[18];
  float* out = (float*)d_out;

  // allow 128 KiB dynamic LDS for the 8-phase GEMMs (idempotent, capture-safe)
  hipFuncSetAttribute((const void*)k_gemm256<8>,
      hipFuncAttributeMaxDynamicSharedMemorySize, 131072);
  hipFuncSetAttribute((const void*)k_gemm256<6>,
      hipFuncAttributeMaxDynamicSharedMemorySize, 131072);
  hipFuncSetAttribute((const void*)k_gemm256<9>,
      hipFuncAttributeMaxDynamicSharedMemorySize, 131072);

  char* p = (char*)d_ws;
  auto alloc = [&](size_t elems, size_t esz) -> char* {
    char* r = p; p += (elems * esz + 255) & ~(size_t)255; return r;
  };
  short* WqkvT = (short*)alloc((size_t)LNUM * 3 * DD * DD, 2);  // [L][3][D][D]
  short* WpT = (short*)alloc((size_t)LNUM * DD * DD, 2);
  short* W1T = (short*)alloc((size_t)LNUM * DD * FF, 2);
  short* W2T = (short*)alloc((size_t)LNUM * DD * FF, 2);
  short* WhT = (short*)alloc((size_t)DD * VV, 2);
  float* xf   = (float*)alloc((size_t)MROWS * DD, 4);   // fp32 residual stream
  float* ff   = (float*)alloc((size_t)MROWS * DD, 4);
  short* xb   = (short*)alloc((size_t)MROWS * DD, 2);
  short* ab   = (short*)alloc((size_t)MROWS * DD, 2);
  short* qkvb = (short*)alloc((size_t)3 * MROWS * DD, 2); // q | k | v^T contiguous
  short* obuf = (short*)alloc((size_t)MROWS * DD, 2);
  short* hb   = (short*)alloc((size_t)MROWS * FF, 2);
  short* xfb  = (short*)alloc((size_t)MROWS * DD, 2);
  short* prob = (short*)alloc((size_t)BB * HH * SS * SS, 2);
  short* qb   = qkvb;
  short* kb   = qkvb + (size_t)MROWS * DD;
  short* vtb  = qkvb + (size_t)2 * MROWS * DD;

  dim3 blk(256);
  dim3 t8(32, 8);
  const long long DD2 = (long long)DD * DD;
  k_tcvt<<<dim3(DD / 32, DD / 32, LNUM), t8, 0, stream>>>(Wq, WqkvT,          DD, DD, 3 * DD2);
  k_tcvt<<<dim3(DD / 32, DD / 32, LNUM), t8, 0, stream>>>(Wk, WqkvT + DD2,    DD, DD, 3 * DD2);
  k_tcvt<<<dim3(DD / 32, DD / 32, LNUM), t8, 0, stream>>>(Wv, WqkvT + 2*DD2,  DD, DD, 3 * DD2);
  k_tcvt<<<dim3(DD / 32, DD / 32, LNUM), t8, 0, stream>>>(Wp, WpT, DD, DD, DD2);
  k_tcvt<<<dim3(FF / 32, DD / 32, LNUM), t8, 0, stream>>>(W1, W1T, DD, FF, (long long)DD * FF);
  k_tcvt<<<dim3(DD / 32, FF / 32, LNUM), t8, 0, stream>>>(W2, W2T, FF, DD, (long long)DD * FF);
  k_tcvt<<<dim3(VV / 32, DD / 32, 1),   t8, 0, stream>>>(Wh, WhT, DD, VV, 0);

  k_embed<<<(MROWS * DD / 4) / 256, blk, 0, stream>>>(tokens, tok_emb, pos_emb, xf, xb);

  for (int l = 0; l < LNUM; l++) {
    const short* wqkv = WqkvT + (size_t)l * 3 * DD * DD;
    const short* wp = WpT + (size_t)l * DD * DD;
    const short* w1 = W1T + (size_t)l * DD * FF;
    const short* w2 = W2T + (size_t)l * DD * FF;

    // fused QKV projection: [4096 x 3072 x 1024] on 8-phase 256^2
    k_gemm256<8><<<dim3(12, 16), 512, 131072, stream>>>(xb, wqkv, nullptr, qkvb,
        MROWS, 3 * DD, DD, DD, DD);
    // fused scores+softmax -> bf16 probs
    k_qksm<<<dim3(8, BB * HH), blk, 0, stream>>>(qb, kb, prob);
    // o[b,h] = P @ V   (A=probs [S,S], Bt=v^T [HD,S])
    k_gemm<4><<<dim3(1, 8, BB * HH), blk, 0, stream>>>(prob, vtb, nullptr, obuf,
        SS, HDD, SS, SS, SS, (long long)SS * SS, (long long)HDD * SS);
    // proj (N=1024 -> 128^2 kernel)
    k_gemm<5><<<dim3(8, 32, 1), blk, 0, stream>>>(obuf, wp, nullptr, ff,
        MROWS, DD, DD, DD, DD, 0, 0);
    k_ln<1, 0><<<MROWS, blk, 0, stream>>>(ff, xf, ln1s + (size_t)l * DD,
        ln1b + (size_t)l * DD, nullptr, ab);
    // ffn1: [4096 x 4096 x 1024] on 8-phase 256^2
    k_gemm256<6><<<dim3(16, 16), 512, 131072, stream>>>(ab, w1, b1 + (size_t)l * FF, hb,
        MROWS, FF, DD, DD, DD);
    // ffn2 (N=1024 -> 128^2 kernel)
    k_gemm<7><<<dim3(8, 32, 1), blk, 0, stream>>>(hb, w2, b2 + (size_t)l * DD, ff,
        MROWS, DD, FF, FF, FF, 0, 0);
    k_ln<1, 1><<<MROWS, blk, 0, stream>>>(ff, xf, ln2s + (size_t)l * DD,
        ln2b + (size_t)l * DD, xf, xb);
  }

  k_ln<0, 0><<<MROWS, blk, 0, stream>>>(xf, nullptr, lnfs, lnfb, nullptr, xfb);
  // logits = lnf(x) @ Wh + bh : [4096 x 32000 x 1024] on 8-phase 256^2
  k_gemm256<9><<<dim3(VV / 256, 16), 512, 131072, stream>>>(xfb, WhT, bh, out,
      MROWS, VV, DD, DD, DD);
}

// Round 4
// 2442.857 us; speedup vs baseline: 1.4784x; 1.1478x over previous
//
#include <hip/hip_runtime.h>

#define DEV __device__ __forceinline__

typedef __attribute__((ext_vector_type(4))) float f32x4;
typedef __attribute__((ext_vector_type(8))) short short8_t;

constexpr int LNUM = 6;
constexpr int BB = 4;
constexpr int SS = 1024;
constexpr int DD = 1024;
constexpr int HH = 16;
constexpr int HDD = 64;
constexpr int FF = 4096;
constexpr int VV = 32000;
constexpr int MROWS = BB * SS;   // 4096

DEV short f2bf(float f) {
  union { float f; unsigned u; } x; x.f = f;
  unsigned r = x.u + 0x7fffu + ((x.u >> 16) & 1u);   // RNE
  return (short)(r >> 16);
}

#define BAR() do { __builtin_amdgcn_sched_barrier(0); \
  __builtin_amdgcn_s_barrier(); \
  __builtin_amdgcn_sched_barrier(0); } while (0)

// ---------------- embedding: x = tok_emb[tok] + pos_emb ----------------
__global__ __launch_bounds__(256) void k_embed(
    const int* __restrict__ tok, const float* __restrict__ te,
    const float* __restrict__ pe, float* __restrict__ xf,
    short* __restrict__ xb) {
  int i = blockIdx.x * 256 + threadIdx.x;            // over MROWS*DD/4
  int bs = i >> 8, d4 = i & 255;
  int t = tok[bs];
  float4 a = ((const float4*)(te + (size_t)t * DD))[d4];
  float4 b = ((const float4*)(pe + (size_t)(bs & (SS - 1)) * DD))[d4];
  float4 r; r.x = a.x + b.x; r.y = a.y + b.y; r.z = a.z + b.z; r.w = a.w + b.w;
  ((float4*)xf)[i] = r;
  short4 o; o.x = f2bf(r.x); o.y = f2bf(r.y); o.z = f2bf(r.z); o.w = f2bf(r.w);
  ((short4*)xb)[i] = o;
}

// ------- transpose + fp32->bf16: W[K,N] -> Wt[N,K] bf16, out stride per z -------
__global__ __launch_bounds__(256) void k_tcvt(
    const float* __restrict__ in, short* __restrict__ out, int K, int N,
    long long ostride) {
  __shared__ float tile[32][33];
  const float* ip = in + (size_t)blockIdx.z * K * N;
  short* op = out + (size_t)blockIdx.z * ostride;
  int bn = blockIdx.x * 32, bk = blockIdx.y * 32;
  int tx = threadIdx.x, ty = threadIdx.y;            // (32,8)
  #pragma unroll
  for (int r = 0; r < 32; r += 8)
    tile[ty + r][tx] = ip[(size_t)(bk + ty + r) * N + bn + tx];
  __syncthreads();
  #pragma unroll
  for (int r = 0; r < 32; r += 8)
    op[(size_t)(bn + ty + r) * K + bk + tx] = f2bf(tile[tx][ty + r]);
}

DEV void gload16(const short* g, short* l) {
  __builtin_amdgcn_global_load_lds(
      (const __attribute__((address_space(1))) void*)g,
      (__attribute__((address_space(3))) void*)l, 16, 0, 0);
}

// ============ 256x256 8-phase bf16 GEMM (T2+T3+T4+T5), BK=64 ============
// A[M,K] bf16 row-major, Bt[N,K] bf16 row-major. 512 thr = 8 waves (2M x 4N).
// LDS 128 KiB dynamic: [buf][A 256x64 | B 256x64]. Swizzle byte^=((row&7)<<4)
// on stage-source + ds_read (rule #21). Counted vmcnt(8) once per K-window.
// MODEs: 5 fp32; 6 relu+bias->bf16; 7 fp32+bias; 8 fused QKV.
// Requires M%256==0, N%256==0, K%64==0, K/64>=2, gridDim.y==16, nwg%8==0.
template<int MODE>
__global__ __launch_bounds__(512, 2) void k_gemm256(
    const short* __restrict__ A, const short* __restrict__ Bt,
    const float* __restrict__ bias, void* __restrict__ Cp,
    int M, int N, int K, int lda, int ldb) {
  extern __shared__ short lds[];
  const int tid = threadIdx.x;
  // XCD-bijective swizzle, N-major chunks (full-M per XCD chunk -> L2 reuse)
  const int nbx = gridDim.x;
  const int nwg = nbx << 4;
  const int hid = blockIdx.y * nbx + blockIdx.x;
  const int cpx = nwg >> 3;
  const int lid = (hid & 7) * cpx + (hid >> 3);
  const int bx = lid >> 4, by = lid & 15;
  const int n0 = bx * 256, m0 = by * 256;

  const int lane = tid & 63;
  const int wid = tid >> 6;
  const int wm = wid >> 2, wn = wid & 3;
  const int l16 = lane & 15, kg = lane >> 4;
  const int xorv = (l16 & 7) << 4;                    // byte-col XOR for reads
  const int cs[2] = { ((kg << 4) ^ xorv) >> 1,
                      ((64 | (kg << 4)) ^ xorv) >> 1 };
  const int rr = tid >> 3;                            // 0..63
  const int sce = ((((tid & 7) << 4) ^ ((rr & 7) << 4)) >> 1);
  const int ldst = (tid & ~63) * 8;                   // wave-uniform elem base

  const int NT = K >> 6;

  auto stageA = [&](int t2, int c2) {
    const int k0 = t2 << 6;
    const int base = c2 * 32768;
    #pragma unroll
    for (int h = 0; h < 2; h++)
      #pragma unroll
      for (int li = 0; li < 2; li++)
        gload16(A + (size_t)(m0 + h * 128 + li * 64 + rr) * lda + k0 + sce,
                &lds[base + h * 8192 + li * 4096 + ldst]);
  };
  auto stageB = [&](int t2, int c2) {
    const int k0 = t2 << 6;
    const int base = c2 * 32768 + 16384;
    #pragma unroll
    for (int h = 0; h < 2; h++)
      #pragma unroll
      for (int li = 0; li < 2; li++)
        gload16(Bt + (size_t)(n0 + h * 128 + li * 64 + rr) * ldb + k0 + sce,
                &lds[base + h * 8192 + li * 4096 + ldst]);
  };

  f32x4 acc[8][4];
  #pragma unroll
  for (int mi = 0; mi < 8; mi++)
    #pragma unroll
    for (int ni = 0; ni < 4; ni++)
      #pragma unroll
      for (int j = 0; j < 4; j++) acc[mi][ni][j] = 0.f;

  stageA(0, 0); stageB(0, 0);
  stageA(1, 1); stageB(1, 1);
  asm volatile("s_waitcnt vmcnt(8)" ::: "memory");
  BAR();

  for (int t = 0; t < NT; t++) {
    const int c = t & 1;
    const int ao = c * 32768 + wm * 8192;
    const int bo = c * 32768 + 16384 + (wn >> 1) * 8192 + (wn & 1) * 4096;
    short8_t a[4][2], b0[2][2], b1[2][2];

    // ---- P0: read a_lo (8) + b0 (4); MFMA (lo x n0-1) ----
    #pragma unroll
    for (int mi = 0; mi < 4; mi++)
      #pragma unroll
      for (int kk = 0; kk < 2; kk++)
        a[mi][kk] = *(const short8_t*)&lds[ao + (mi * 16 + l16) * 64 + cs[kk]];
    #pragma unroll
    for (int ni = 0; ni < 2; ni++)
      #pragma unroll
      for (int kk = 0; kk < 2; kk++)
        b0[ni][kk] = *(const short8_t*)&lds[bo + (ni * 16 + l16) * 64 + cs[kk]];
    BAR();
    __builtin_amdgcn_s_setprio(1);
    #pragma unroll
    for (int mi = 0; mi < 4; mi++)
      #pragma unroll
      for (int ni = 0; ni < 2; ni++)
        #pragma unroll
        for (int kk = 0; kk < 2; kk++)
          acc[mi][ni] = __builtin_amdgcn_mfma_f32_16x16x32_bf16(
              a[mi][kk], b0[ni][kk], acc[mi][ni], 0, 0, 0);
    __builtin_amdgcn_s_setprio(0);
    BAR();

    // ---- P1: read b1 (4); MFMA (lo x n2-3) ----
    #pragma unroll
    for (int ni = 0; ni < 2; ni++)
      #pragma unroll
      for (int kk = 0; kk < 2; kk++)
        b1[ni][kk] = *(const short8_t*)&lds[bo + ((ni + 2) * 16 + l16) * 64 + cs[kk]];
    BAR();
    __builtin_amdgcn_s_setprio(1);
    #pragma unroll
    for (int mi = 0; mi < 4; mi++)
      #pragma unroll
      for (int ni = 0; ni < 2; ni++)
        #pragma unroll
        for (int kk = 0; kk < 2; kk++)
          acc[mi][ni + 2] = __builtin_amdgcn_mfma_f32_16x16x32_bf16(
              a[mi][kk], b1[ni][kk], acc[mi][ni + 2], 0, 0, 0);
    __builtin_amdgcn_s_setprio(0);
    BAR();                 // B slots of buf c consumed by all waves

    // ---- P2: read a_hi (8); stage B(t+2)->buf c; MFMA (hi x n2-3) ----
    #pragma unroll
    for (int mi = 0; mi < 4; mi++)
      #pragma unroll
      for (int kk = 0; kk < 2; kk++)
        a[mi][kk] = *(const short8_t*)&lds[ao + ((mi + 4) * 16 + l16) * 64 + cs[kk]];
    if (t + 2 < NT) stageB(t + 2, c);
    BAR();
    __builtin_amdgcn_s_setprio(1);
    #pragma unroll
    for (int mi = 0; mi < 4; mi++)
      #pragma unroll
      for (int ni = 0; ni < 2; ni++)
        #pragma unroll
        for (int kk = 0; kk < 2; kk++)
          acc[mi + 4][ni + 2] = __builtin_amdgcn_mfma_f32_16x16x32_bf16(
              a[mi][kk], b1[ni][kk], acc[mi + 4][ni + 2], 0, 0, 0);
    __builtin_amdgcn_s_setprio(0);
    BAR();                 // A slots of buf c consumed

    // ---- P3: stage A(t+2)->buf c; MFMA (hi x n0-1); counted vmcnt ----
    if (t + 2 < NT) stageA(t + 2, c);
    BAR();
    __builtin_amdgcn_s_setprio(1);
    #pragma unroll
    for (int mi = 0; mi < 4; mi++)
      #pragma unroll
      for (int ni = 0; ni < 2; ni++)
        #pragma unroll
        for (int kk = 0; kk < 2; kk++)
          acc[mi + 4][ni] = __builtin_amdgcn_mfma_f32_16x16x32_bf16(
              a[mi][kk], b0[ni][kk], acc[mi + 4][ni], 0, 0, 0);
    __builtin_amdgcn_s_setprio(0);
    if (t + 2 < NT) asm volatile("s_waitcnt vmcnt(8)" ::: "memory");
    else            asm volatile("s_waitcnt vmcnt(0)" ::: "memory");
    BAR();                 // next window may read buf ~c
  }

  // ---- epilogue ----
  #pragma unroll
  for (int mi = 0; mi < 8; mi++) {
    #pragma unroll
    for (int ni = 0; ni < 4; ni++) {
      #pragma unroll
      for (int j = 0; j < 4; j++) {
        const int r = m0 + wm * 128 + mi * 16 + kg * 4 + j;
        const int c = n0 + wn * 64 + ni * 16 + l16;
        const float v = acc[mi][ni][j];
        if (MODE == 5) {
          ((float*)Cp)[(size_t)r * N + c] = v;
        } else if (MODE == 6) {
          ((short*)Cp)[(size_t)r * N + c] = f2bf(fmaxf(v + bias[c], 0.f));
        } else if (MODE == 7) {
          ((float*)Cp)[(size_t)r * N + c] = v + bias[c];
        } else if (MODE == 8) {
          int kind = c >> 10, cc = c & 1023;
          int b = r >> 10, s = r & 1023, h = cc >> 6, hd = cc & 63;
          size_t off;
          if (kind < 2)
            off = (size_t)kind * MROWS * DD +
                  (((size_t)(b * HH + h) << 10) + s) * HDD + hd;
          else
            off = (size_t)2 * MROWS * DD +
                  (((size_t)(b * HH + h) * HDD + hd) << 10) + s;
          ((short*)Cp)[off] = f2bf(v);
        }
      }
    }
  }
}

// ======== one-pass flash attention: O = softmax(causal(QK^T/8)) V ========
// grid (8 qblocks, B*H), 256 thr = 4 waves, each wave owns 32 q-rows.
// LDS (dynamic 80 KiB): Q[128][64] K[128][64] V^T[64][128] (byte-XOR swz,
// staged via pre-swizzled gload source) + P[128][128] per-wave-private
// (short-XOR swz; written and read by the same wave -> no barrier needed).
#define RDSWZ(arr, r, cb) \
  (*(const short8_t*)&arr[((r) << 6) + ((((cb) ^ (((r) & 7) << 4))) >> 1)])
#define RDSWZ7(arr, r, cb) \
  (*(const short8_t*)&arr[((r) << 7) + ((((cb) ^ (((r) & 7) << 4))) >> 1)])

__global__ __launch_bounds__(256, 2) void k_attn(
    const short* __restrict__ Qg, const short* __restrict__ Kgl,
    const short* __restrict__ Vt, short* __restrict__ Og) {
  extern __shared__ short sm[];
  short* lQ = sm;            // [128][64]
  short* lK = sm + 8192;     // [128][64]
  short* lV = sm + 16384;    // [64][128]
  short* lP = sm + 24576;    // [128][128]
  const int tid = threadIdx.x;
  const int qb = blockIdx.x, z = blockIdx.y;
  const int q0 = qb << 7;
  const short* Qp = Qg + ((size_t)z << 16);   // [S][64]
  const short* Kp = Kgl + ((size_t)z << 16);  // [S][64]
  const short* Vp = Vt + ((size_t)z << 16);   // [64][S]
  const int bidx = z >> 4, h = z & 15;
  const int lane = tid & 63, w = tid >> 6;
  const int l16 = lane & 15, kg = lane >> 4;
  const int sr = tid >> 3;                    // Q/K staging: 8 thr/row
  const int scb = ((((tid & 7) << 4) ^ ((sr & 7) << 4)) >> 1);
  const int vr = tid >> 4;                    // V staging: 16 thr/row
  const int vcb = ((((tid & 15) << 4) ^ ((vr & 7) << 4)) >> 1);
  const int ldst = (tid & ~63) << 3;          // wave-uniform elem base

  #pragma unroll
  for (int i = 0; i < 4; i++)
    gload16(Qp + ((size_t)(q0 + i * 32 + sr) << 6) + scb, &lQ[i * 2048 + ldst]);

  f32x4 acc_o[2][4];
  float m_r[2][4], l_r[2][4];
  #pragma unroll
  for (int mi = 0; mi < 2; mi++)
    #pragma unroll
    for (int j = 0; j < 4; j++) {
      m_r[mi][j] = -3e38f; l_r[mi][j] = 0.f;
      #pragma unroll
      for (int n2 = 0; n2 < 4; n2++) acc_o[mi][n2][j] = 0.f;
    }

  const int nkt = qb + 1;
  for (int kt = 0; kt < nkt; kt++) {
    const int k0 = kt << 7;
    #pragma unroll
    for (int i = 0; i < 4; i++)
      gload16(Kp + ((size_t)(k0 + i * 32 + sr) << 6) + scb, &lK[i * 2048 + ldst]);
    #pragma unroll
    for (int i = 0; i < 4; i++)
      gload16(Vp + ((size_t)(i * 16 + vr) << 10) + k0 + vcb, &lV[i * 2048 + ldst]);
    __syncthreads();                           // drains vmcnt

    // ---- S = Q K^T ----
    f32x4 s[2][8];
    #pragma unroll
    for (int mi = 0; mi < 2; mi++)
      #pragma unroll
      for (int nf = 0; nf < 8; nf++)
        #pragma unroll
        for (int j = 0; j < 4; j++) s[mi][nf][j] = 0.f;
    #pragma unroll
    for (int kk = 0; kk < 2; kk++) {
      short8_t aq[2];
      #pragma unroll
      for (int mi = 0; mi < 2; mi++)
        aq[mi] = RDSWZ(lQ, w * 32 + mi * 16 + l16, kk * 64 + kg * 16);
      #pragma unroll
      for (int nf = 0; nf < 8; nf++) {
        short8_t bk = RDSWZ(lK, nf * 16 + l16, kk * 64 + kg * 16);
        #pragma unroll
        for (int mi = 0; mi < 2; mi++)
          s[mi][nf] = __builtin_amdgcn_mfma_f32_16x16x32_bf16(
              aq[mi], bk, s[mi][nf], 0, 0, 0);
      }
    }

    // ---- online softmax update + P~ write ----
    const bool diag = (kt == qb);
    #pragma unroll
    for (int mi = 0; mi < 2; mi++) {
      #pragma unroll
      for (int j = 0; j < 4; j++) {
        const int ql = w * 32 + mi * 16 + kg * 4 + j;
        const int q = q0 + ql;
        float sv[8]; float tm = -3e38f;
        #pragma unroll
        for (int nf = 0; nf < 8; nf++) {
          int kv = k0 + nf * 16 + l16;
          sv[nf] = (!diag || kv <= q) ? s[mi][nf][j] * 0.125f : -3e38f;
          tm = fmaxf(tm, sv[nf]);
        }
        #pragma unroll
        for (int o = 1; o < 16; o <<= 1) tm = fmaxf(tm, __shfl_xor(tm, o));
        const float mn = fmaxf(m_r[mi][j], tm);
        const float scale = __expf(m_r[mi][j] - mn);
        float e[8]; float ts = 0.f;
        #pragma unroll
        for (int nf = 0; nf < 8; nf++) { e[nf] = __expf(sv[nf] - mn); ts += e[nf]; }
        #pragma unroll
        for (int o = 1; o < 16; o <<= 1) ts += __shfl_xor(ts, o);
        l_r[mi][j] = l_r[mi][j] * scale + ts;
        m_r[mi][j] = mn;
        #pragma unroll
        for (int n2 = 0; n2 < 4; n2++) acc_o[mi][n2][j] *= scale;
        #pragma unroll
        for (int nf = 0; nf < 8; nf++)
          lP[(ql << 7) + ((nf * 16 + l16) ^ ((ql & 7) << 3))] = f2bf(e[nf]);
      }
    }

    // ---- O += P~ V  (P read by same wave that wrote it) ----
    #pragma unroll
    for (int kc = 0; kc < 4; kc++) {
      short8_t pa[2];
      #pragma unroll
      for (int mi = 0; mi < 2; mi++) {
        const int pr = w * 32 + mi * 16 + l16;
        pa[mi] = *(const short8_t*)
            &lP[(pr << 7) + ((kc * 32 + kg * 8) ^ ((pr & 7) << 3))];
      }
      #pragma unroll
      for (int n2 = 0; n2 < 4; n2++) {
        short8_t vb = RDSWZ7(lV, n2 * 16 + l16, kc * 64 + kg * 16);
        #pragma unroll
        for (int mi = 0; mi < 2; mi++)
          acc_o[mi][n2] = __builtin_amdgcn_mfma_f32_16x16x32_bf16(
              pa[mi], vb, acc_o[mi][n2], 0, 0, 0);
      }
    }
    __syncthreads();                           // before next K/V overwrite
  }

  // ---- normalize + write O[b, s, h*64 + hd] ----
  #pragma unroll
  for (int mi = 0; mi < 2; mi++) {
    #pragma unroll
    for (int j = 0; j < 4; j++) {
      const int q = q0 + w * 32 + mi * 16 + kg * 4 + j;
      const float inv = 1.f / l_r[mi][j];
      #pragma unroll
      for (int n2 = 0; n2 < 4; n2++) {
        const int col = h * HDD + n2 * 16 + l16;
        Og[(((size_t)bidx << 10) + q) * DD + col] = f2bf(acc_o[mi][n2][j] * inv);
      }
    }
  }
}

// ---------------- LayerNorm (D=1024) with optional residual ----------------
template<int ADD_RES, int WRITE_F32>
__global__ __launch_bounds__(256) void k_ln(
    const float* __restrict__ src, const float* __restrict__ res,
    const float* __restrict__ g, const float* __restrict__ b,
    float* __restrict__ of, short* __restrict__ ob) {
  const int row = blockIdx.x;
  const int tid = threadIdx.x;
  float4 v = ((const float4*)(src + ((size_t)row << 10)))[tid];
  float s1 = v.x + v.y + v.z + v.w;
  float s2 = v.x * v.x + v.y * v.y + v.z * v.z + v.w * v.w;
  #pragma unroll
  for (int o = 32; o; o >>= 1) { s1 += __shfl_xor(s1, o); s2 += __shfl_xor(s2, o); }
  __shared__ float sh1[4], sh2[4];
  if ((tid & 63) == 0) { sh1[tid >> 6] = s1; sh2[tid >> 6] = s2; }
  __syncthreads();
  s1 = sh1[0] + sh1[1] + sh1[2] + sh1[3];
  s2 = sh2[0] + sh2[1] + sh2[2] + sh2[3];
  const float mean = s1 * (1.f / 1024.f);
  const float var  = s2 * (1.f / 1024.f) - mean * mean;
  const float rs = rsqrtf(var + 1e-5f);
  float4 gg = ((const float4*)g)[tid];
  float4 bb = ((const float4*)b)[tid];
  float4 o4;
  o4.x = (v.x - mean) * rs * gg.x + bb.x;
  o4.y = (v.y - mean) * rs * gg.y + bb.y;
  o4.z = (v.z - mean) * rs * gg.z + bb.z;
  o4.w = (v.w - mean) * rs * gg.w + bb.w;
  if (ADD_RES) {
    float4 rr = ((const float4*)(res + ((size_t)row << 10)))[tid];
    o4.x += rr.x; o4.y += rr.y; o4.z += rr.z; o4.w += rr.w;
  }
  if (WRITE_F32) ((float4*)(of + ((size_t)row << 10)))[tid] = o4;
  short4 s4; s4.x = f2bf(o4.x); s4.y = f2bf(o4.y);
  s4.z = f2bf(o4.z); s4.w = f2bf(o4.w);
  ((short4*)ob)[((size_t)row << 8) + tid] = s4;
}

extern "C" void kernel_launch(void* const* d_in, const int* in_sizes, int n_in,
                              void* d_out, int out_size, void* d_ws, size_t ws_size,
                              hipStream_t stream) {
  (void)in_sizes; (void)n_in; (void)out_size; (void)ws_size;
  const int*   tokens  = (const int*)d_in[0];
  const float* tok_emb = (const float*)d_in[1];
  const float* pos_emb = (const float*)d_in[2];
  const float* Wq = (const float*)d_in[3];
  const float* Wk = (const float*)d_in[4];
  const float* Wv = (const float*)d_in[5];
  const float* Wp = (const float*)d_in[6];
  const float* ln1s = (const float*)d_in[7];
  const float* ln1b = (const float*)d_in[8];
  const float* W1 = (const float*)d_in[9];
  const float* b1 = (const float*)d_in[10];
  const float* W2 = (const float*)d_in[11];
  const float* b2 = (const float*)d_in[12];
  const float* ln2s = (const float*)d_in[13];
  const float* ln2b = (const float*)d_in[14];
  const float* lnfs = (const float*)d_in[15];
  const float* lnfb = (const float*)d_in[16];
  const float* Wh = (const float*)d_in[17];
  const float* bh = (const float*)d_in[18];
  float* out = (float*)d_out;

  hipFuncSetAttribute((const void*)k_gemm256<5>,
      hipFuncAttributeMaxDynamicSharedMemorySize, 131072);
  hipFuncSetAttribute((const void*)k_gemm256<6>,
      hipFuncAttributeMaxDynamicSharedMemorySize, 131072);
  hipFuncSetAttribute((const void*)k_gemm256<7>,
      hipFuncAttributeMaxDynamicSharedMemorySize, 131072);
  hipFuncSetAttribute((const void*)k_gemm256<8>,
      hipFuncAttributeMaxDynamicSharedMemorySize, 131072);
  hipFuncSetAttribute((const void*)k_attn,
      hipFuncAttributeMaxDynamicSharedMemorySize, 81920);

  char* p = (char*)d_ws;
  auto alloc = [&](size_t elems, size_t esz) -> char* {
    char* r = p; p += (elems * esz + 255) & ~(size_t)255; return r;
  };
  short* WqkvT = (short*)alloc((size_t)LNUM * 3 * DD * DD, 2);  // [L][3][D][D]
  short* WpT = (short*)alloc((size_t)LNUM * DD * DD, 2);
  short* W1T = (short*)alloc((size_t)LNUM * DD * FF, 2);
  short* W2T = (short*)alloc((size_t)LNUM * DD * FF, 2);
  short* WhT = (short*)alloc((size_t)DD * VV, 2);
  float* xf   = (float*)alloc((size_t)MROWS * DD, 4);   // fp32 residual stream
  float* ff   = (float*)alloc((size_t)MROWS * DD, 4);
  short* xb   = (short*)alloc((size_t)MROWS * DD, 2);
  short* ab   = (short*)alloc((size_t)MROWS * DD, 2);
  short* qkvb = (short*)alloc((size_t)3 * MROWS * DD, 2); // q | k | v^T contiguous
  short* obuf = (short*)alloc((size_t)MROWS * DD, 2);
  short* hb   = (short*)alloc((size_t)MROWS * FF, 2);
  short* xfb  = (short*)alloc((size_t)MROWS * DD, 2);
  short* qb   = qkvb;
  short* kb   = qkvb + (size_t)MROWS * DD;
  short* vtb  = qkvb + (size_t)2 * MROWS * DD;

  dim3 blk(256);
  dim3 t8(32, 8);
  const long long DD2 = (long long)DD * DD;
  k_tcvt<<<dim3(DD / 32, DD / 32, LNUM), t8, 0, stream>>>(Wq, WqkvT,          DD, DD, 3 * DD2);
  k_tcvt<<<dim3(DD / 32, DD / 32, LNUM), t8, 0, stream>>>(Wk, WqkvT + DD2,    DD, DD, 3 * DD2);
  k_tcvt<<<dim3(DD / 32, DD / 32, LNUM), t8, 0, stream>>>(Wv, WqkvT + 2*DD2,  DD, DD, 3 * DD2);
  k_tcvt<<<dim3(DD / 32, DD / 32, LNUM), t8, 0, stream>>>(Wp, WpT, DD, DD, DD2);
  k_tcvt<<<dim3(FF / 32, DD / 32, LNUM), t8, 0, stream>>>(W1, W1T, DD, FF, (long long)DD * FF);
  k_tcvt<<<dim3(DD / 32, FF / 32, LNUM), t8, 0, stream>>>(W2, W2T, FF, DD, (long long)DD * FF);
  k_tcvt<<<dim3(VV / 32, DD / 32, 1),   t8, 0, stream>>>(Wh, WhT, DD, VV, 0);

  k_embed<<<(MROWS * DD / 4) / 256, blk, 0, stream>>>(tokens, tok_emb, pos_emb, xf, xb);

  for (int l = 0; l < LNUM; l++) {
    const short* wqkv = WqkvT + (size_t)l * 3 * DD * DD;
    const short* wp = WpT + (size_t)l * DD * DD;
    const short* w1 = W1T + (size_t)l * DD * FF;
    const short* w2 = W2T + (size_t)l * DD * FF;

    // fused QKV projection: [4096 x 3072 x 1024]
    k_gemm256<8><<<dim3(12, 16), 512, 131072, stream>>>(xb, wqkv, nullptr, qkvb,
        MROWS, 3 * DD, DD, DD, DD);
    // one-pass flash attention -> obuf [B,S,D]
    k_attn<<<dim3(8, BB * HH), blk, 81920, stream>>>(qb, kb, vtb, obuf);
    // proj: [4096 x 1024 x 1024]
    k_gemm256<5><<<dim3(4, 16), 512, 131072, stream>>>(obuf, wp, nullptr, ff,
        MROWS, DD, DD, DD, DD);
    k_ln<1, 0><<<MROWS, blk, 0, stream>>>(ff, xf, ln1s + (size_t)l * DD,
        ln1b + (size_t)l * DD, nullptr, ab);
    // ffn1: [4096 x 4096 x 1024]
    k_gemm256<6><<<dim3(16, 16), 512, 131072, stream>>>(ab, w1, b1 + (size_t)l * FF, hb,
        MROWS, FF, DD, DD, DD);
    // ffn2: [4096 x 1024 x 4096]
    k_gemm256<7><<<dim3(4, 16), 512, 131072, stream>>>(hb, w2, b2 + (size_t)l * DD, ff,
        MROWS, DD, FF, FF, FF);
    k_ln<1, 1><<<MROWS, blk, 0, stream>>>(ff, xf, ln2s + (size_t)l * DD,
        ln2b + (size_t)l * DD, xf, xb);
  }

  k_ln<0, 0><<<MROWS, blk, 0, stream>>>(xf, nullptr, lnfs, lnfb, nullptr, xfb);
  // logits = lnf(x) @ Wh + bh : [4096 x 32000 x 1024]
  k_gemm256<7><<<dim3(VV / 256, 16), 512, 131072, stream>>>(xfb, WhT, bh, out,
      MROWS, VV, DD, DD, DD);
}

// Round 5
// 2417.905 us; speedup vs baseline: 1.4937x; 1.0103x over previous
//
#include <hip/hip_runtime.h>

#define DEV __device__ __forceinline__

typedef __attribute__((ext_vector_type(4))) float f32x4;
typedef __attribute__((ext_vector_type(8))) short short8_t;

constexpr int LNUM = 6;
constexpr int BB = 4;
constexpr int SS = 1024;
constexpr int DD = 1024;
constexpr int HH = 16;
constexpr int HDD = 64;
constexpr int FF = 4096;
constexpr int VV = 32000;
constexpr int MROWS = BB * SS;   // 4096

DEV short f2bf(float f) {
  union { float f; unsigned u; } x; x.f = f;
  unsigned r = x.u + 0x7fffu + ((x.u >> 16) & 1u);   // RNE
  return (short)(r >> 16);
}

#define BAR() do { __builtin_amdgcn_sched_barrier(0); \
  __builtin_amdgcn_s_barrier(); \
  __builtin_amdgcn_sched_barrier(0); } while (0)

// ---------------- embedding: x = tok_emb[tok] + pos_emb ----------------
__global__ __launch_bounds__(256) void k_embed(
    const int* __restrict__ tok, const float* __restrict__ te,
    const float* __restrict__ pe, float* __restrict__ xf,
    short* __restrict__ xb) {
  int i = blockIdx.x * 256 + threadIdx.x;            // over MROWS*DD/4
  int bs = i >> 8, d4 = i & 255;
  int t = tok[bs];
  float4 a = ((const float4*)(te + (size_t)t * DD))[d4];
  float4 b = ((const float4*)(pe + (size_t)(bs & (SS - 1)) * DD))[d4];
  float4 r; r.x = a.x + b.x; r.y = a.y + b.y; r.z = a.z + b.z; r.w = a.w + b.w;
  ((float4*)xf)[i] = r;
  short4 o; o.x = f2bf(r.x); o.y = f2bf(r.y); o.z = f2bf(r.z); o.w = f2bf(r.w);
  ((short4*)xb)[i] = o;
}

// ------- transpose + fp32->bf16: W[K,N] -> Wt[N,K] bf16, out stride per z -------
__global__ __launch_bounds__(256) void k_tcvt(
    const float* __restrict__ in, short* __restrict__ out, int K, int N,
    long long ostride) {
  __shared__ float tile[32][33];
  const float* ip = in + (size_t)blockIdx.z * K * N;
  short* op = out + (size_t)blockIdx.z * ostride;
  int bn = blockIdx.x * 32, bk = blockIdx.y * 32;
  int tx = threadIdx.x, ty = threadIdx.y;            // (32,8)
  #pragma unroll
  for (int r = 0; r < 32; r += 8)
    tile[ty + r][tx] = ip[(size_t)(bk + ty + r) * N + bn + tx];
  __syncthreads();
  #pragma unroll
  for (int r = 0; r < 32; r += 8)
    op[(size_t)(bn + ty + r) * K + bk + tx] = f2bf(tile[tx][ty + r]);
}

DEV void gload16(const short* g, short* l) {
  __builtin_amdgcn_global_load_lds(
      (const __attribute__((address_space(1))) void*)g,
      (__attribute__((address_space(3))) void*)l, 16, 0, 0);
}

// ============ 256x256 8-phase bf16 GEMM (T2+T3+T4+T5), BK=64 ============
// A[M,K] bf16 row-major, Bt[N,K] bf16 row-major. 512 thr = 8 waves (2M x 4N).
// LDS 128 KiB dynamic: [buf][A 256x64 | B 256x64]. Swizzle byte^=((row&7)<<4)
// on stage-source + ds_read (rule #21). Counted vmcnt(8) once per K-window.
// MODEs: 6 relu+bias->bf16; 8 fused QKV; 9 fp32+bias with INTERLEAVED epilogue
// (each acc quadrant is final after its phase of the last K-tile; stores
// overlap the remaining phases' MFMA since staging slots are empty there).
// Requires M%256==0, N%256==0, K%64==0, K/64>=2, gridDim.y==16, nwg%8==0.
template<int MODE>
__global__ __launch_bounds__(512, 2) void k_gemm256(
    const short* __restrict__ A, const short* __restrict__ Bt,
    const float* __restrict__ bias, void* __restrict__ Cp,
    int M, int N, int K, int lda, int ldb) {
  extern __shared__ short lds[];
  const int tid = threadIdx.x;
  // XCD-bijective swizzle, N-major chunks (full-M per XCD chunk -> L2 reuse)
  const int nbx = gridDim.x;
  const int nwg = nbx << 4;
  const int hid = blockIdx.y * nbx + blockIdx.x;
  const int cpx = nwg >> 3;
  const int lid = (hid & 7) * cpx + (hid >> 3);
  const int bx = lid >> 4, by = lid & 15;
  const int n0 = bx * 256, m0 = by * 256;

  const int lane = tid & 63;
  const int wid = tid >> 6;
  const int wm = wid >> 2, wn = wid & 3;
  const int l16 = lane & 15, kg = lane >> 4;
  const int xorv = (l16 & 7) << 4;                    // byte-col XOR for reads
  const int cs[2] = { ((kg << 4) ^ xorv) >> 1,
                      ((64 | (kg << 4)) ^ xorv) >> 1 };
  const int rr = tid >> 3;                            // 0..63
  const int sce = ((((tid & 7) << 4) ^ ((rr & 7) << 4)) >> 1);
  const int ldst = (tid & ~63) * 8;                   // wave-uniform elem base

  const int NT = K >> 6;

  auto stageA = [&](int t2, int c2) {
    const int k0 = t2 << 6;
    const int base = c2 * 32768;
    #pragma unroll
    for (int h = 0; h < 2; h++)
      #pragma unroll
      for (int li = 0; li < 2; li++)
        gload16(A + (size_t)(m0 + h * 128 + li * 64 + rr) * lda + k0 + sce,
                &lds[base + h * 8192 + li * 4096 + ldst]);
  };
  auto stageB = [&](int t2, int c2) {
    const int k0 = t2 << 6;
    const int base = c2 * 32768 + 16384;
    #pragma unroll
    for (int h = 0; h < 2; h++)
      #pragma unroll
      for (int li = 0; li < 2; li++)
        gload16(Bt + (size_t)(n0 + h * 128 + li * 64 + rr) * ldb + k0 + sce,
                &lds[base + h * 8192 + li * 4096 + ldst]);
  };

  f32x4 acc[8][4];
  #pragma unroll
  for (int mi = 0; mi < 8; mi++)
    #pragma unroll
    for (int ni = 0; ni < 4; ni++)
      #pragma unroll
      for (int j = 0; j < 4; j++) acc[mi][ni][j] = 0.f;

  // quadrant store for MODE 9 (fp32 + bias)
  auto storeQ = [&](int mlo, int nlo) {
    #pragma unroll
    for (int mi = 0; mi < 4; mi++)
      #pragma unroll
      for (int ni = 0; ni < 2; ni++)
        #pragma unroll
        for (int j = 0; j < 4; j++) {
          const int r = m0 + wm * 128 + (mlo + mi) * 16 + kg * 4 + j;
          const int c = n0 + wn * 64 + (nlo + ni) * 16 + l16;
          ((float*)Cp)[(size_t)r * N + c] = acc[mlo + mi][nlo + ni][j] + bias[c];
        }
  };

  stageA(0, 0); stageB(0, 0);
  stageA(1, 1); stageB(1, 1);
  asm volatile("s_waitcnt vmcnt(8)" ::: "memory");
  BAR();

  for (int t = 0; t < NT; t++) {
    const int c = t & 1;
    const int ao = c * 32768 + wm * 8192;
    const int bo = c * 32768 + 16384 + (wn >> 1) * 8192 + (wn & 1) * 4096;
    short8_t a[4][2], b0[2][2], b1[2][2];

    // ---- P0: read a_lo (8) + b0 (4); MFMA (lo x n0-1) ----
    #pragma unroll
    for (int mi = 0; mi < 4; mi++)
      #pragma unroll
      for (int kk = 0; kk < 2; kk++)
        a[mi][kk] = *(const short8_t*)&lds[ao + (mi * 16 + l16) * 64 + cs[kk]];
    #pragma unroll
    for (int ni = 0; ni < 2; ni++)
      #pragma unroll
      for (int kk = 0; kk < 2; kk++)
        b0[ni][kk] = *(const short8_t*)&lds[bo + (ni * 16 + l16) * 64 + cs[kk]];
    BAR();
    __builtin_amdgcn_s_setprio(1);
    #pragma unroll
    for (int mi = 0; mi < 4; mi++)
      #pragma unroll
      for (int ni = 0; ni < 2; ni++)
        #pragma unroll
        for (int kk = 0; kk < 2; kk++)
          acc[mi][ni] = __builtin_amdgcn_mfma_f32_16x16x32_bf16(
              a[mi][kk], b0[ni][kk], acc[mi][ni], 0, 0, 0);
    __builtin_amdgcn_s_setprio(0);
    if (MODE == 9 && t == NT - 1) storeQ(0, 0);
    BAR();

    // ---- P1: read b1 (4); MFMA (lo x n2-3) ----
    #pragma unroll
    for (int ni = 0; ni < 2; ni++)
      #pragma unroll
      for (int kk = 0; kk < 2; kk++)
        b1[ni][kk] = *(const short8_t*)&lds[bo + ((ni + 2) * 16 + l16) * 64 + cs[kk]];
    BAR();
    __builtin_amdgcn_s_setprio(1);
    #pragma unroll
    for (int mi = 0; mi < 4; mi++)
      #pragma unroll
      for (int ni = 0; ni < 2; ni++)
        #pragma unroll
        for (int kk = 0; kk < 2; kk++)
          acc[mi][ni + 2] = __builtin_amdgcn_mfma_f32_16x16x32_bf16(
              a[mi][kk], b1[ni][kk], acc[mi][ni + 2], 0, 0, 0);
    __builtin_amdgcn_s_setprio(0);
    if (MODE == 9 && t == NT - 1) storeQ(0, 2);
    BAR();                 // B slots of buf c consumed by all waves

    // ---- P2: read a_hi (8); stage B(t+2)->buf c; MFMA (hi x n2-3) ----
    #pragma unroll
    for (int mi = 0; mi < 4; mi++)
      #pragma unroll
      for (int kk = 0; kk < 2; kk++)
        a[mi][kk] = *(const short8_t*)&lds[ao + ((mi + 4) * 16 + l16) * 64 + cs[kk]];
    if (t + 2 < NT) stageB(t + 2, c);
    BAR();
    __builtin_amdgcn_s_setprio(1);
    #pragma unroll
    for (int mi = 0; mi < 4; mi++)
      #pragma unroll
      for (int ni = 0; ni < 2; ni++)
        #pragma unroll
        for (int kk = 0; kk < 2; kk++)
          acc[mi + 4][ni + 2] = __builtin_amdgcn_mfma_f32_16x16x32_bf16(
              a[mi][kk], b1[ni][kk], acc[mi + 4][ni + 2], 0, 0, 0);
    __builtin_amdgcn_s_setprio(0);
    if (MODE == 9 && t == NT - 1) storeQ(4, 2);
    BAR();                 // A slots of buf c consumed

    // ---- P3: stage A(t+2)->buf c; MFMA (hi x n0-1); counted vmcnt ----
    if (t + 2 < NT) stageA(t + 2, c);
    BAR();
    __builtin_amdgcn_s_setprio(1);
    #pragma unroll
    for (int mi = 0; mi < 4; mi++)
      #pragma unroll
      for (int ni = 0; ni < 2; ni++)
        #pragma unroll
        for (int kk = 0; kk < 2; kk++)
          acc[mi + 4][ni] = __builtin_amdgcn_mfma_f32_16x16x32_bf16(
              a[mi][kk], b0[ni][kk], acc[mi + 4][ni], 0, 0, 0);
    __builtin_amdgcn_s_setprio(0);
    if (t + 2 < NT) asm volatile("s_waitcnt vmcnt(8)" ::: "memory");
    else            asm volatile("s_waitcnt vmcnt(0)" ::: "memory");
    BAR();                 // next window may read buf ~c
  }

  // ---- epilogue ----
  if (MODE == 9) {
    storeQ(4, 0);          // last quadrant (finalized in final P3)
    return;
  }
  #pragma unroll
  for (int mi = 0; mi < 8; mi++) {
    #pragma unroll
    for (int ni = 0; ni < 4; ni++) {
      #pragma unroll
      for (int j = 0; j < 4; j++) {
        const int r = m0 + wm * 128 + mi * 16 + kg * 4 + j;
        const int c = n0 + wn * 64 + ni * 16 + l16;
        const float v = acc[mi][ni][j];
        if (MODE == 6) {
          ((short*)Cp)[(size_t)r * N + c] = f2bf(fmaxf(v + bias[c], 0.f));
        } else if (MODE == 8) {
          int kind = c >> 10, cc = c & 1023;
          int b = r >> 10, s = r & 1023, h = cc >> 6, hd = cc & 63;
          size_t off;
          if (kind < 2)
            off = (size_t)kind * MROWS * DD +
                  (((size_t)(b * HH + h) << 10) + s) * HDD + hd;
          else
            off = (size_t)2 * MROWS * DD +
                  (((size_t)(b * HH + h) * HDD + hd) << 10) + s;
          ((short*)Cp)[off] = f2bf(v);
        }
      }
    }
  }
}

// -------- bf16 MFMA GEMM, 2-phase 128x128 tile, BK=32 (N<=1024 shapes) --------
// MODEs: 5 fp32; 7 fp32 x+bias. 256 blocks for M=4096/N=1024 -> full chip.
template<int MODE>
__global__ __launch_bounds__(256) void k_gemm(
    const short* __restrict__ A, const short* __restrict__ Bt,
    const float* __restrict__ bias, void* __restrict__ Cp,
    int M, int N, int K, int lda, int ldb) {
  __shared__ short lA[4096];
  __shared__ short lB[4096];
  const int tid = threadIdx.x;
  const int n0 = blockIdx.x * 128, m0 = blockIdx.y * 128;

  const int lane = tid & 63;
  const int wm = (tid >> 6) >> 1, wn = (tid >> 6) & 1;
  const int l16 = lane & 15, kg = lane >> 4;
  const int srow = tid >> 2, scol = (tid & 3) * 8;
  const int lbase = (tid & ~63) * 8;

  f32x4 acc[4][4];
  #pragma unroll
  for (int a = 0; a < 4; a++)
    #pragma unroll
    for (int b = 0; b < 4; b++)
      #pragma unroll
      for (int j = 0; j < 4; j++) acc[a][b][j] = 0.f;

  for (int k0 = 0; k0 < K; k0 += 32) {
    #pragma unroll
    for (int i = 0; i < 2; i++)
      gload16(A + (size_t)(m0 + i * 64 + srow) * lda + (k0 + scol),
              &lA[i * 2048 + lbase]);
    #pragma unroll
    for (int i = 0; i < 2; i++)
      gload16(Bt + (size_t)(n0 + i * 64 + srow) * ldb + (k0 + scol),
              &lB[i * 2048 + lbase]);
    __syncthreads();
    short8_t af[4], bf[4];
    #pragma unroll
    for (int mi = 0; mi < 4; mi++)
      af[mi] = *(const short8_t*)&lA[(wm * 64 + mi * 16 + l16) * 32 + kg * 8];
    #pragma unroll
    for (int ni = 0; ni < 4; ni++)
      bf[ni] = *(const short8_t*)&lB[(wn * 64 + ni * 16 + l16) * 32 + kg * 8];
    #pragma unroll
    for (int mi = 0; mi < 4; mi++)
      #pragma unroll
      for (int ni = 0; ni < 4; ni++)
        acc[mi][ni] = __builtin_amdgcn_mfma_f32_16x16x32_bf16(
            af[mi], bf[ni], acc[mi][ni], 0, 0, 0);
    __syncthreads();
  }

  #pragma unroll
  for (int mi = 0; mi < 4; mi++) {
    #pragma unroll
    for (int ni = 0; ni < 4; ni++) {
      #pragma unroll
      for (int j = 0; j < 4; j++) {
        const int r = m0 + wm * 64 + mi * 16 + kg * 4 + j;
        const int c = n0 + wn * 64 + ni * 16 + l16;
        const float v = acc[mi][ni][j];
        if (MODE == 5) {
          ((float*)Cp)[(size_t)r * N + c] = v;
        } else if (MODE == 7) {
          ((float*)Cp)[(size_t)r * N + c] = v + bias[c];
        }
      }
    }
  }
}

// ======== one-pass flash attention: O = softmax(causal(QK^T/8)) V ========
// grid (8 qblocks, B*H), 256 thr = 4 waves, each wave owns 32 q-rows.
// LDS (dynamic 80 KiB): Q[128][64] K[128][64] V^T[64][128] (byte-XOR swz,
// staged via pre-swizzled gload source) + P[128][128] per-wave-private
// (short-XOR swz; written and read by the same wave -> no barrier needed).
// qb load-pairing: blocks i and i+256 (likely same CU) get qb and 7-qb,
// so each CU's two blocks total ~9 k-tiles instead of up to 16.
#define RDSWZ(arr, r, cb) \
  (*(const short8_t*)&arr[((r) << 6) + ((((cb) ^ (((r) & 7) << 4))) >> 1)])
#define RDSWZ7(arr, r, cb) \
  (*(const short8_t*)&arr[((r) << 7) + ((((cb) ^ (((r) & 7) << 4))) >> 1)])

__global__ __launch_bounds__(256, 2) void k_attn(
    const short* __restrict__ Qg, const short* __restrict__ Kgl,
    const short* __restrict__ Vt, short* __restrict__ Og) {
  extern __shared__ short sm[];
  short* lQ = sm;            // [128][64]
  short* lK = sm + 8192;     // [128][64]
  short* lV = sm + 16384;    // [64][128]
  short* lP = sm + 24576;    // [128][128]
  const int tid = threadIdx.x;
  const int z = blockIdx.y;
  const int qb = (z < 32) ? blockIdx.x : 7 - blockIdx.x;
  const int q0 = qb << 7;
  const short* Qp = Qg + ((size_t)z << 16);   // [S][64]
  const short* Kp = Kgl + ((size_t)z << 16);  // [S][64]
  const short* Vp = Vt + ((size_t)z << 16);   // [64][S]
  const int bidx = z >> 4, h = z & 15;
  const int lane = tid & 63, w = tid >> 6;
  const int l16 = lane & 15, kg = lane >> 4;
  const int sr = tid >> 3;                    // Q/K staging: 8 thr/row
  const int scb = ((((tid & 7) << 4) ^ ((sr & 7) << 4)) >> 1);
  const int vr = tid >> 4;                    // V staging: 16 thr/row
  const int vcb = ((((tid & 15) << 4) ^ ((vr & 7) << 4)) >> 1);
  const int ldst = (tid & ~63) << 3;          // wave-uniform elem base

  #pragma unroll
  for (int i = 0; i < 4; i++)
    gload16(Qp + ((size_t)(q0 + i * 32 + sr) << 6) + scb, &lQ[i * 2048 + ldst]);

  f32x4 acc_o[2][4];
  float m_r[2][4], l_r[2][4];
  #pragma unroll
  for (int mi = 0; mi < 2; mi++)
    #pragma unroll
    for (int j = 0; j < 4; j++) {
      m_r[mi][j] = -3e38f; l_r[mi][j] = 0.f;
      #pragma unroll
      for (int n2 = 0; n2 < 4; n2++) acc_o[mi][n2][j] = 0.f;
    }

  const int nkt = qb + 1;
  for (int kt = 0; kt < nkt; kt++) {
    const int k0 = kt << 7;
    #pragma unroll
    for (int i = 0; i < 4; i++)
      gload16(Kp + ((size_t)(k0 + i * 32 + sr) << 6) + scb, &lK[i * 2048 + ldst]);
    #pragma unroll
    for (int i = 0; i < 4; i++)
      gload16(Vp + ((size_t)(i * 16 + vr) << 10) + k0 + vcb, &lV[i * 2048 + ldst]);
    __syncthreads();                           // drains vmcnt

    // ---- S = Q K^T ----
    f32x4 s[2][8];
    #pragma unroll
    for (int mi = 0; mi < 2; mi++)
      #pragma unroll
      for (int nf = 0; nf < 8; nf++)
        #pragma unroll
        for (int j = 0; j < 4; j++) s[mi][nf][j] = 0.f;
    #pragma unroll
    for (int kk = 0; kk < 2; kk++) {
      short8_t aq[2];
      #pragma unroll
      for (int mi = 0; mi < 2; mi++)
        aq[mi] = RDSWZ(lQ, w * 32 + mi * 16 + l16, kk * 64 + kg * 16);
      #pragma unroll
      for (int nf = 0; nf < 8; nf++) {
        short8_t bk = RDSWZ(lK, nf * 16 + l16, kk * 64 + kg * 16);
        #pragma unroll
        for (int mi = 0; mi < 2; mi++)
          s[mi][nf] = __builtin_amdgcn_mfma_f32_16x16x32_bf16(
              aq[mi], bk, s[mi][nf], 0, 0, 0);
      }
    }

    // ---- online softmax update + P~ write ----
    const bool diag = (kt == qb);
    #pragma unroll
    for (int mi = 0; mi < 2; mi++) {
      #pragma unroll
      for (int j = 0; j < 4; j++) {
        const int ql = w * 32 + mi * 16 + kg * 4 + j;
        const int q = q0 + ql;
        float sv[8]; float tm = -3e38f;
        #pragma unroll
        for (int nf = 0; nf < 8; nf++) {
          int kv = k0 + nf * 16 + l16;
          sv[nf] = (!diag || kv <= q) ? s[mi][nf][j] * 0.125f : -3e38f;
          tm = fmaxf(tm, sv[nf]);
        }
        #pragma unroll
        for (int o = 1; o < 16; o <<= 1) tm = fmaxf(tm, __shfl_xor(tm, o));
        const float mn = fmaxf(m_r[mi][j], tm);
        const float scale = __expf(m_r[mi][j] - mn);
        float e[8]; float ts = 0.f;
        #pragma unroll
        for (int nf = 0; nf < 8; nf++) { e[nf] = __expf(sv[nf] - mn); ts += e[nf]; }
        #pragma unroll
        for (int o = 1; o < 16; o <<= 1) ts += __shfl_xor(ts, o);
        l_r[mi][j] = l_r[mi][j] * scale + ts;
        m_r[mi][j] = mn;
        #pragma unroll
        for (int n2 = 0; n2 < 4; n2++) acc_o[mi][n2][j] *= scale;
        #pragma unroll
        for (int nf = 0; nf < 8; nf++)
          lP[(ql << 7) + ((nf * 16 + l16) ^ ((ql & 7) << 3))] = f2bf(e[nf]);
      }
    }

    // ---- O += P~ V  (P read by same wave that wrote it) ----
    #pragma unroll
    for (int kc = 0; kc < 4; kc++) {
      short8_t pa[2];
      #pragma unroll
      for (int mi = 0; mi < 2; mi++) {
        const int pr = w * 32 + mi * 16 + l16;
        pa[mi] = *(const short8_t*)
            &lP[(pr << 7) + ((kc * 32 + kg * 8) ^ ((pr & 7) << 3))];
      }
      #pragma unroll
      for (int n2 = 0; n2 < 4; n2++) {
        short8_t vb = RDSWZ7(lV, n2 * 16 + l16, kc * 64 + kg * 16);
        #pragma unroll
        for (int mi = 0; mi < 2; mi++)
          acc_o[mi][n2] = __builtin_amdgcn_mfma_f32_16x16x32_bf16(
              pa[mi], vb, acc_o[mi][n2], 0, 0, 0);
      }
    }
    __syncthreads();                           // before next K/V overwrite
  }

  // ---- normalize + write O[b, s, h*64 + hd] ----
  #pragma unroll
  for (int mi = 0; mi < 2; mi++) {
    #pragma unroll
    for (int j = 0; j < 4; j++) {
      const int q = q0 + w * 32 + mi * 16 + kg * 4 + j;
      const float inv = 1.f / l_r[mi][j];
      #pragma unroll
      for (int n2 = 0; n2 < 4; n2++) {
        const int col = h * HDD + n2 * 16 + l16;
        Og[(((size_t)bidx << 10) + q) * DD + col] = f2bf(acc_o[mi][n2][j] * inv);
      }
    }
  }
}

// ---------------- LayerNorm (D=1024) with optional residual ----------------
template<int ADD_RES, int WRITE_F32>
__global__ __launch_bounds__(256) void k_ln(
    const float* __restrict__ src, const float* __restrict__ res,
    const float* __restrict__ g, const float* __restrict__ b,
    float* __restrict__ of, short* __restrict__ ob) {
  const int row = blockIdx.x;
  const int tid = threadIdx.x;
  float4 v = ((const float4*)(src + ((size_t)row << 10)))[tid];
  float s1 = v.x + v.y + v.z + v.w;
  float s2 = v.x * v.x + v.y * v.y + v.z * v.z + v.w * v.w;
  #pragma unroll
  for (int o = 32; o; o >>= 1) { s1 += __shfl_xor(s1, o); s2 += __shfl_xor(s2, o); }
  __shared__ float sh1[4], sh2[4];
  if ((tid & 63) == 0) { sh1[tid >> 6] = s1; sh2[tid >> 6] = s2; }
  __syncthreads();
  s1 = sh1[0] + sh1[1] + sh1[2] + sh1[3];
  s2 = sh2[0] + sh2[1] + sh2[2] + sh2[3];
  const float mean = s1 * (1.f / 1024.f);
  const float var  = s2 * (1.f / 1024.f) - mean * mean;
  const float rs = rsqrtf(var + 1e-5f);
  float4 gg = ((const float4*)g)[tid];
  float4 bb = ((const float4*)b)[tid];
  float4 o4;
  o4.x = (v.x - mean) * rs * gg.x + bb.x;
  o4.y = (v.y - mean) * rs * gg.y + bb.y;
  o4.z = (v.z - mean) * rs * gg.z + bb.z;
  o4.w = (v.w - mean) * rs * gg.w + bb.w;
  if (ADD_RES) {
    float4 rr = ((const float4*)(res + ((size_t)row << 10)))[tid];
    o4.x += rr.x; o4.y += rr.y; o4.z += rr.z; o4.w += rr.w;
  }
  if (WRITE_F32) ((float4*)(of + ((size_t)row << 10)))[tid] = o4;
  short4 s4; s4.x = f2bf(o4.x); s4.y = f2bf(o4.y);
  s4.z = f2bf(o4.z); s4.w = f2bf(o4.w);
  ((short4*)ob)[((size_t)row << 8) + tid] = s4;
}

extern "C" void kernel_launch(void* const* d_in, const int* in_sizes, int n_in,
                              void* d_out, int out_size, void* d_ws, size_t ws_size,
                              hipStream_t stream) {
  (void)in_sizes; (void)n_in; (void)out_size; (void)ws_size;
  const int*   tokens  = (const int*)d_in[0];
  const float* tok_emb = (const float*)d_in[1];
  const float* pos_emb = (const float*)d_in[2];
  const float* Wq = (const float*)d_in[3];
  const float* Wk = (const float*)d_in[4];
  const float* Wv = (const float*)d_in[5];
  const float* Wp = (const float*)d_in[6];
  const float* ln1s = (const float*)d_in[7];
  const float* ln1b = (const float*)d_in[8];
  const float* W1 = (const float*)d_in[9];
  const float* b1 = (const float*)d_in[10];
  const float* W2 = (const float*)d_in[11];
  const float* b2 = (const float*)d_in[12];
  const float* ln2s = (const float*)d_in[13];
  const float* ln2b = (const float*)d_in[14];
  const float* lnfs = (const float*)d_in[15];
  const float* lnfb = (const float*)d_in[16];
  const float* Wh = (const float*)d_in[17];
  const float* bh = (const float*)d_in[18];
  float* out = (float*)d_out;

  hipFuncSetAttribute((const void*)k_gemm256<6>,
      hipFuncAttributeMaxDynamicSharedMemorySize, 131072);
  hipFuncSetAttribute((const void*)k_gemm256<8>,
      hipFuncAttributeMaxDynamicSharedMemorySize, 131072);
  hipFuncSetAttribute((const void*)k_gemm256<9>,
      hipFuncAttributeMaxDynamicSharedMemorySize, 131072);
  hipFuncSetAttribute((const void*)k_attn,
      hipFuncAttributeMaxDynamicSharedMemorySize, 81920);

  char* p = (char*)d_ws;
  auto alloc = [&](size_t elems, size_t esz) -> char* {
    char* r = p; p += (elems * esz + 255) & ~(size_t)255; return r;
  };
  short* WqkvT = (short*)alloc((size_t)LNUM * 3 * DD * DD, 2);  // [L][3][D][D]
  short* WpT = (short*)alloc((size_t)LNUM * DD * DD, 2);
  short* W1T = (short*)alloc((size_t)LNUM * DD * FF, 2);
  short* W2T = (short*)alloc((size_t)LNUM * DD * FF, 2);
  short* WhT = (short*)alloc((size_t)DD * VV, 2);
  float* xf   = (float*)alloc((size_t)MROWS * DD, 4);   // fp32 residual stream
  float* ff   = (float*)alloc((size_t)MROWS * DD, 4);
  short* xb   = (short*)alloc((size_t)MROWS * DD, 2);
  short* ab   = (short*)alloc((size_t)MROWS * DD, 2);
  short* qkvb = (short*)alloc((size_t)3 * MROWS * DD, 2); // q | k | v^T contiguous
  short* obuf = (short*)alloc((size_t)MROWS * DD, 2);
  short* hb   = (short*)alloc((size_t)MROWS * FF, 2);
  short* xfb  = (short*)alloc((size_t)MROWS * DD, 2);
  short* qb   = qkvb;
  short* kb   = qkvb + (size_t)MROWS * DD;
  short* vtb  = qkvb + (size_t)2 * MROWS * DD;

  dim3 blk(256);
  dim3 t8(32, 8);
  const long long DD2 = (long long)DD * DD;
  k_tcvt<<<dim3(DD / 32, DD / 32, LNUM), t8, 0, stream>>>(Wq, WqkvT,          DD, DD, 3 * DD2);
  k_tcvt<<<dim3(DD / 32, DD / 32, LNUM), t8, 0, stream>>>(Wk, WqkvT + DD2,    DD, DD, 3 * DD2);
  k_tcvt<<<dim3(DD / 32, DD / 32, LNUM), t8, 0, stream>>>(Wv, WqkvT + 2*DD2,  DD, DD, 3 * DD2);
  k_tcvt<<<dim3(DD / 32, DD / 32, LNUM), t8, 0, stream>>>(Wp, WpT, DD, DD, DD2);
  k_tcvt<<<dim3(FF / 32, DD / 32, LNUM), t8, 0, stream>>>(W1, W1T, DD, FF, (long long)DD * FF);
  k_tcvt<<<dim3(DD / 32, FF / 32, LNUM), t8, 0, stream>>>(W2, W2T, FF, DD, (long long)DD * FF);
  k_tcvt<<<dim3(VV / 32, DD / 32, 1),   t8, 0, stream>>>(Wh, WhT, DD, VV, 0);

  k_embed<<<(MROWS * DD / 4) / 256, blk, 0, stream>>>(tokens, tok_emb, pos_emb, xf, xb);

  for (int l = 0; l < LNUM; l++) {
    const short* wqkv = WqkvT + (size_t)l * 3 * DD * DD;
    const short* wp = WpT + (size_t)l * DD * DD;
    const short* w1 = W1T + (size_t)l * DD * FF;
    const short* w2 = W2T + (size_t)l * DD * FF;

    // fused QKV projection: [4096 x 3072 x 1024]
    k_gemm256<8><<<dim3(12, 16), 512, 131072, stream>>>(xb, wqkv, nullptr, qkvb,
        MROWS, 3 * DD, DD, DD, DD);
    // one-pass flash attention -> obuf [B,S,D]
    k_attn<<<dim3(8, BB * HH), blk, 81920, stream>>>(qb, kb, vtb, obuf);
    // proj: [4096 x 1024 x 1024] on 2-phase 128^2 (256 wg -> full chip)
    k_gemm<5><<<dim3(8, 32), blk, 0, stream>>>(obuf, wp, nullptr, ff,
        MROWS, DD, DD, DD, DD);
    k_ln<1, 0><<<MROWS, blk, 0, stream>>>(ff, xf, ln1s + (size_t)l * DD,
        ln1b + (size_t)l * DD, nullptr, ab);
    // ffn1: [4096 x 4096 x 1024]
    k_gemm256<6><<<dim3(16, 16), 512, 131072, stream>>>(ab, w1, b1 + (size_t)l * FF, hb,
        MROWS, FF, DD, DD, DD);
    // ffn2: [4096 x 1024 x 4096] on 2-phase 128^2
    k_gemm<7><<<dim3(8, 32), blk, 0, stream>>>(hb, w2, b2 + (size_t)l * DD, ff,
        MROWS, DD, FF, FF, FF);
    k_ln<1, 1><<<MROWS, blk, 0, stream>>>(ff, xf, ln2s + (size_t)l * DD,
        ln2b + (size_t)l * DD, xf, xb);
  }

  k_ln<0, 0><<<MROWS, blk, 0, stream>>>(xf, nullptr, lnfs, lnfb, nullptr, xfb);
  // logits = lnf(x) @ Wh + bh : [4096 x 32000 x 1024], interleaved epilogue
  k_gemm256<9><<<dim3(VV / 256, 16), 512, 131072, stream>>>(xfb, WhT, bh, out,
      MROWS, VV, DD, DD, DD);
}

// Round 6
// 2397.749 us; speedup vs baseline: 1.5062x; 1.0084x over previous
//
#include <hip/hip_runtime.h>

#define DEV __device__ __forceinline__

typedef __attribute__((ext_vector_type(4))) float f32x4;
typedef __attribute__((ext_vector_type(8))) short short8_t;

constexpr int LNUM = 6;
constexpr int BB = 4;
constexpr int SS = 1024;
constexpr int DD = 1024;
constexpr int HH = 16;
constexpr int HDD = 64;
constexpr int FF = 4096;
constexpr int VV = 32000;
constexpr int MROWS = BB * SS;   // 4096

DEV short f2bf(float f) {
  union { float f; unsigned u; } x; x.f = f;
  unsigned r = x.u + 0x7fffu + ((x.u >> 16) & 1u);   // RNE
  return (short)(r >> 16);
}

#define BAR() do { __builtin_amdgcn_sched_barrier(0); \
  __builtin_amdgcn_s_barrier(); \
  __builtin_amdgcn_sched_barrier(0); } while (0)

// ---------------- embedding: x = tok_emb[tok] + pos_emb ----------------
__global__ __launch_bounds__(256) void k_embed(
    const int* __restrict__ tok, const float* __restrict__ te,
    const float* __restrict__ pe, float* __restrict__ xf,
    short* __restrict__ xb) {
  int i = blockIdx.x * 256 + threadIdx.x;            // over MROWS*DD/4
  int bs = i >> 8, d4 = i & 255;
  int t = tok[bs];
  float4 a = ((const float4*)(te + (size_t)t * DD))[d4];
  float4 b = ((const float4*)(pe + (size_t)(bs & (SS - 1)) * DD))[d4];
  float4 r; r.x = a.x + b.x; r.y = a.y + b.y; r.z = a.z + b.z; r.w = a.w + b.w;
  ((float4*)xf)[i] = r;
  short4 o; o.x = f2bf(r.x); o.y = f2bf(r.y); o.z = f2bf(r.z); o.w = f2bf(r.w);
  ((short4*)xb)[i] = o;
}

// ------- transpose + fp32->bf16: W[K,N] -> Wt[N,K] bf16, out stride per z -------
__global__ __launch_bounds__(256) void k_tcvt(
    const float* __restrict__ in, short* __restrict__ out, int K, int N,
    long long ostride) {
  __shared__ float tile[32][33];
  const float* ip = in + (size_t)blockIdx.z * K * N;
  short* op = out + (size_t)blockIdx.z * ostride;
  int bn = blockIdx.x * 32, bk = blockIdx.y * 32;
  int tx = threadIdx.x, ty = threadIdx.y;            // (32,8)
  #pragma unroll
  for (int r = 0; r < 32; r += 8)
    tile[ty + r][tx] = ip[(size_t)(bk + ty + r) * N + bn + tx];
  __syncthreads();
  #pragma unroll
  for (int r = 0; r < 32; r += 8)
    op[(size_t)(bn + ty + r) * K + bk + tx] = f2bf(tile[tx][ty + r]);
}

DEV void gload16(const short* g, short* l) {
  __builtin_amdgcn_global_load_lds(
      (const __attribute__((address_space(1))) void*)g,
      (__attribute__((address_space(3))) void*)l, 16, 0, 0);
}

// ============ 256x256 8-phase bf16 GEMM (T2+T3+T4+T5), BK=64 ============
// A[M,K] bf16 row-major, Bt[N,K] bf16 row-major. 512 thr = 8 waves (2M x 4N).
// LDS 128 KiB dynamic: [buf][A 256x64 | B 256x64]. Swizzle byte^=((row&7)<<4)
// on stage-source + ds_read (rule #21). Counted vmcnt(8) once per K-window.
// MODEs: 6 relu+bias->bf16; 8 fused QKV; 9 fp32+bias with interleaved epilogue.
// Requires M%256==0, N%256==0, K%64==0, K/64>=2, gridDim.y==16, nwg%8==0.
template<int MODE>
__global__ __launch_bounds__(512, 2) void k_gemm256(
    const short* __restrict__ A, const short* __restrict__ Bt,
    const float* __restrict__ bias, void* __restrict__ Cp,
    int M, int N, int K, int lda, int ldb) {
  extern __shared__ short lds[];
  const int tid = threadIdx.x;
  // XCD-bijective swizzle, N-major chunks (full-M per XCD chunk -> L2 reuse)
  const int nbx = gridDim.x;
  const int nwg = nbx << 4;
  const int hid = blockIdx.y * nbx + blockIdx.x;
  const int cpx = nwg >> 3;
  const int lid = (hid & 7) * cpx + (hid >> 3);
  const int bx = lid >> 4, by = lid & 15;
  const int n0 = bx * 256, m0 = by * 256;

  const int lane = tid & 63;
  const int wid = tid >> 6;
  const int wm = wid >> 2, wn = wid & 3;
  const int l16 = lane & 15, kg = lane >> 4;
  const int xorv = (l16 & 7) << 4;                    // byte-col XOR for reads
  const int cs[2] = { ((kg << 4) ^ xorv) >> 1,
                      ((64 | (kg << 4)) ^ xorv) >> 1 };
  const int rr = tid >> 3;                            // 0..63
  const int sce = ((((tid & 7) << 4) ^ ((rr & 7) << 4)) >> 1);
  const int ldst = (tid & ~63) * 8;                   // wave-uniform elem base

  const int NT = K >> 6;

  auto stageA = [&](int t2, int c2) {
    const int k0 = t2 << 6;
    const int base = c2 * 32768;
    #pragma unroll
    for (int h = 0; h < 2; h++)
      #pragma unroll
      for (int li = 0; li < 2; li++)
        gload16(A + (size_t)(m0 + h * 128 + li * 64 + rr) * lda + k0 + sce,
                &lds[base + h * 8192 + li * 4096 + ldst]);
  };
  auto stageB = [&](int t2, int c2) {
    const int k0 = t2 << 6;
    const int base = c2 * 32768 + 16384;
    #pragma unroll
    for (int h = 0; h < 2; h++)
      #pragma unroll
      for (int li = 0; li < 2; li++)
        gload16(Bt + (size_t)(n0 + h * 128 + li * 64 + rr) * ldb + k0 + sce,
                &lds[base + h * 8192 + li * 4096 + ldst]);
  };

  f32x4 acc[8][4];
  #pragma unroll
  for (int mi = 0; mi < 8; mi++)
    #pragma unroll
    for (int ni = 0; ni < 4; ni++)
      #pragma unroll
      for (int j = 0; j < 4; j++) acc[mi][ni][j] = 0.f;

  // quadrant store for MODE 9 (fp32 + bias)
  auto storeQ = [&](int mlo, int nlo) {
    #pragma unroll
    for (int mi = 0; mi < 4; mi++)
      #pragma unroll
      for (int ni = 0; ni < 2; ni++)
        #pragma unroll
        for (int j = 0; j < 4; j++) {
          const int r = m0 + wm * 128 + (mlo + mi) * 16 + kg * 4 + j;
          const int c = n0 + wn * 64 + (nlo + ni) * 16 + l16;
          ((float*)Cp)[(size_t)r * N + c] = acc[mlo + mi][nlo + ni][j] + bias[c];
        }
  };

  stageA(0, 0); stageB(0, 0);
  stageA(1, 1); stageB(1, 1);
  asm volatile("s_waitcnt vmcnt(8)" ::: "memory");
  BAR();

  for (int t = 0; t < NT; t++) {
    const int c = t & 1;
    const int ao = c * 32768 + wm * 8192;
    const int bo = c * 32768 + 16384 + (wn >> 1) * 8192 + (wn & 1) * 4096;
    short8_t a[4][2], b0[2][2], b1[2][2];

    // ---- P0: read a_lo (8) + b0 (4); MFMA (lo x n0-1) ----
    #pragma unroll
    for (int mi = 0; mi < 4; mi++)
      #pragma unroll
      for (int kk = 0; kk < 2; kk++)
        a[mi][kk] = *(const short8_t*)&lds[ao + (mi * 16 + l16) * 64 + cs[kk]];
    #pragma unroll
    for (int ni = 0; ni < 2; ni++)
      #pragma unroll
      for (int kk = 0; kk < 2; kk++)
        b0[ni][kk] = *(const short8_t*)&lds[bo + (ni * 16 + l16) * 64 + cs[kk]];
    BAR();
    __builtin_amdgcn_s_setprio(1);
    #pragma unroll
    for (int mi = 0; mi < 4; mi++)
      #pragma unroll
      for (int ni = 0; ni < 2; ni++)
        #pragma unroll
        for (int kk = 0; kk < 2; kk++)
          acc[mi][ni] = __builtin_amdgcn_mfma_f32_16x16x32_bf16(
              a[mi][kk], b0[ni][kk], acc[mi][ni], 0, 0, 0);
    __builtin_amdgcn_s_setprio(0);
    if (MODE == 9 && t == NT - 1) storeQ(0, 0);
    BAR();

    // ---- P1: read b1 (4); MFMA (lo x n2-3) ----
    #pragma unroll
    for (int ni = 0; ni < 2; ni++)
      #pragma unroll
      for (int kk = 0; kk < 2; kk++)
        b1[ni][kk] = *(const short8_t*)&lds[bo + ((ni + 2) * 16 + l16) * 64 + cs[kk]];
    BAR();
    __builtin_amdgcn_s_setprio(1);
    #pragma unroll
    for (int mi = 0; mi < 4; mi++)
      #pragma unroll
      for (int ni = 0; ni < 2; ni++)
        #pragma unroll
        for (int kk = 0; kk < 2; kk++)
          acc[mi][ni + 2] = __builtin_amdgcn_mfma_f32_16x16x32_bf16(
              a[mi][kk], b1[ni][kk], acc[mi][ni + 2], 0, 0, 0);
    __builtin_amdgcn_s_setprio(0);
    if (MODE == 9 && t == NT - 1) storeQ(0, 2);
    BAR();                 // B slots of buf c consumed by all waves

    // ---- P2: read a_hi (8); stage B(t+2)->buf c; MFMA (hi x n2-3) ----
    #pragma unroll
    for (int mi = 0; mi < 4; mi++)
      #pragma unroll
      for (int kk = 0; kk < 2; kk++)
        a[mi][kk] = *(const short8_t*)&lds[ao + ((mi + 4) * 16 + l16) * 64 + cs[kk]];
    if (t + 2 < NT) stageB(t + 2, c);
    BAR();
    __builtin_amdgcn_s_setprio(1);
    #pragma unroll
    for (int mi = 0; mi < 4; mi++)
      #pragma unroll
      for (int ni = 0; ni < 2; ni++)
        #pragma unroll
        for (int kk = 0; kk < 2; kk++)
          acc[mi + 4][ni + 2] = __builtin_amdgcn_mfma_f32_16x16x32_bf16(
              a[mi][kk], b1[ni][kk], acc[mi + 4][ni + 2], 0, 0, 0);
    __builtin_amdgcn_s_setprio(0);
    if (MODE == 9 && t == NT - 1) storeQ(4, 2);
    BAR();                 // A slots of buf c consumed

    // ---- P3: stage A(t+2)->buf c; MFMA (hi x n0-1); counted vmcnt ----
    if (t + 2 < NT) stageA(t + 2, c);
    BAR();
    __builtin_amdgcn_s_setprio(1);
    #pragma unroll
    for (int mi = 0; mi < 4; mi++)
      #pragma unroll
      for (int ni = 0; ni < 2; ni++)
        #pragma unroll
        for (int kk = 0; kk < 2; kk++)
          acc[mi + 4][ni] = __builtin_amdgcn_mfma_f32_16x16x32_bf16(
              a[mi][kk], b0[ni][kk], acc[mi + 4][ni], 0, 0, 0);
    __builtin_amdgcn_s_setprio(0);
    if (t + 2 < NT) asm volatile("s_waitcnt vmcnt(8)" ::: "memory");
    else            asm volatile("s_waitcnt vmcnt(0)" ::: "memory");
    BAR();                 // next window may read buf ~c
  }

  // ---- epilogue ----
  if (MODE == 9) {
    storeQ(4, 0);          // last quadrant (finalized in final P3)
    return;
  }
  #pragma unroll
  for (int mi = 0; mi < 8; mi++) {
    #pragma unroll
    for (int ni = 0; ni < 4; ni++) {
      #pragma unroll
      for (int j = 0; j < 4; j++) {
        const int r = m0 + wm * 128 + mi * 16 + kg * 4 + j;
        const int c = n0 + wn * 64 + ni * 16 + l16;
        const float v = acc[mi][ni][j];
        if (MODE == 6) {
          ((short*)Cp)[(size_t)r * N + c] = f2bf(fmaxf(v + bias[c], 0.f));
        } else if (MODE == 8) {
          int kind = c >> 10, cc = c & 1023;
          int b = r >> 10, s = r & 1023, h = cc >> 6, hd = cc & 63;
          size_t off;
          if (kind < 2)
            off = (size_t)kind * MROWS * DD +
                  (((size_t)(b * HH + h) << 10) + s) * HDD + hd;
          else
            off = (size_t)2 * MROWS * DD +
                  (((size_t)(b * HH + h) * HDD + hd) << 10) + s;
          ((short*)Cp)[off] = f2bf(v);
        }
      }
    }
  }
}

// -------- bf16 MFMA GEMM, 2-phase 128x128 tile, BK=32 (N<=1024 shapes) --------
// MODEs: 5 fp32; 7 fp32 x+bias. 256 blocks for M=4096/N=1024 -> full chip.
template<int MODE>
__global__ __launch_bounds__(256) void k_gemm(
    const short* __restrict__ A, const short* __restrict__ Bt,
    const float* __restrict__ bias, void* __restrict__ Cp,
    int M, int N, int K, int lda, int ldb) {
  __shared__ short lA[4096];
  __shared__ short lB[4096];
  const int tid = threadIdx.x;
  const int n0 = blockIdx.x * 128, m0 = blockIdx.y * 128;

  const int lane = tid & 63;
  const int wm = (tid >> 6) >> 1, wn = (tid >> 6) & 1;
  const int l16 = lane & 15, kg = lane >> 4;
  const int srow = tid >> 2, scol = (tid & 3) * 8;
  const int lbase = (tid & ~63) * 8;

  f32x4 acc[4][4];
  #pragma unroll
  for (int a = 0; a < 4; a++)
    #pragma unroll
    for (int b = 0; b < 4; b++)
      #pragma unroll
      for (int j = 0; j < 4; j++) acc[a][b][j] = 0.f;

  for (int k0 = 0; k0 < K; k0 += 32) {
    #pragma unroll
    for (int i = 0; i < 2; i++)
      gload16(A + (size_t)(m0 + i * 64 + srow) * lda + (k0 + scol),
              &lA[i * 2048 + lbase]);
    #pragma unroll
    for (int i = 0; i < 2; i++)
      gload16(Bt + (size_t)(n0 + i * 64 + srow) * ldb + (k0 + scol),
              &lB[i * 2048 + lbase]);
    __syncthreads();
    short8_t af[4], bf[4];
    #pragma unroll
    for (int mi = 0; mi < 4; mi++)
      af[mi] = *(const short8_t*)&lA[(wm * 64 + mi * 16 + l16) * 32 + kg * 8];
    #pragma unroll
    for (int ni = 0; ni < 4; ni++)
      bf[ni] = *(const short8_t*)&lB[(wn * 64 + ni * 16 + l16) * 32 + kg * 8];
    #pragma unroll
    for (int mi = 0; mi < 4; mi++)
      #pragma unroll
      for (int ni = 0; ni < 4; ni++)
        acc[mi][ni] = __builtin_amdgcn_mfma_f32_16x16x32_bf16(
            af[mi], bf[ni], acc[mi][ni], 0, 0, 0);
    __syncthreads();
  }

  #pragma unroll
  for (int mi = 0; mi < 4; mi++) {
    #pragma unroll
    for (int ni = 0; ni < 4; ni++) {
      #pragma unroll
      for (int j = 0; j < 4; j++) {
        const int r = m0 + wm * 64 + mi * 16 + kg * 4 + j;
        const int c = n0 + wn * 64 + ni * 16 + l16;
        const float v = acc[mi][ni][j];
        if (MODE == 5) {
          ((float*)Cp)[(size_t)r * N + c] = v;
        } else if (MODE == 7) {
          ((float*)Cp)[(size_t)r * N + c] = v + bias[c];
        }
      }
    }
  }
}

// ======== flash attention v2: 8 waves, dbuf K/V, Q in regs, exp2 ========
// grid (8 qblocks, B*H), 512 thr = 8 waves, each wave owns 16 q-rows.
// LDS 96 KiB dynamic: [Kbuf0 16K][Vbuf0 16K][Kbuf1 16K][Vbuf1 16K][P 32K].
// Per tile: issue stage(t+1) -> counted vmcnt(4) -> bar -> compute -> bar.
// Q staged once through Kbuf1, read to regs (syncthreads drains lgkm before
// any wave's loop-stage can overwrite). P is wave-private (rows w*16..+16).
#define RDSWZ(arr, r, cb) \
  (*(const short8_t*)&arr[((r) << 6) + ((((cb) ^ (((r) & 7) << 4))) >> 1)])
#define RDSWZ7(arr, r, cb) \
  (*(const short8_t*)&arr[((r) << 7) + ((((cb) ^ (((r) & 7) << 4))) >> 1)])

__global__ __launch_bounds__(512, 2) void k_attn(
    const short* __restrict__ Qg, const short* __restrict__ Kgl,
    const short* __restrict__ Vt, short* __restrict__ Og) {
  extern __shared__ short sm[];
  short* lP = sm + 32768;    // [128][128] swz
  const int tid = threadIdx.x;
  const int z = blockIdx.y;
  const int qb = (z < 32) ? blockIdx.x : 7 - blockIdx.x;  // CU load pairing
  const int q0 = qb << 7;
  const short* Qp = Qg + ((size_t)z << 16);   // [S][64]
  const short* Kp = Kgl + ((size_t)z << 16);  // [S][64]
  const short* Vp = Vt + ((size_t)z << 16);   // [64][S]
  const int bidx = z >> 4, h = z & 15;
  const int lane = tid & 63, w = tid >> 6;    // 8 waves
  const int l16 = lane & 15, kg = lane >> 4;
  const int sr = tid >> 3;                    // K/Q staging: 8 thr/row, 0..63
  const int scb = ((((tid & 7) << 4) ^ ((sr & 7) << 4)) >> 1);
  const int vr = tid >> 4;                    // V staging: 16 thr/row, 0..31
  const int vcb = ((((tid & 15) << 4) ^ ((vr & 7) << 4)) >> 1);
  const int ldst = (tid & ~63) << 3;          // wave-uniform elem base

  auto stageK = [&](int kt, int c) {
    const int k0 = kt << 7;
    short* dst = sm + c * 16384;
    #pragma unroll
    for (int i = 0; i < 2; i++)
      gload16(Kp + ((size_t)(k0 + i * 64 + sr) << 6) + scb,
              dst + i * 4096 + ldst);
  };
  auto stageV = [&](int kt, int c) {
    const int k0 = kt << 7;
    short* dst = sm + c * 16384 + 8192;
    #pragma unroll
    for (int i = 0; i < 2; i++)
      gload16(Vp + ((size_t)(i * 32 + vr) << 10) + k0 + vcb,
              dst + i * 4096 + ldst);
  };

  // ---- stage Q through Kbuf1, read to regs ----
  #pragma unroll
  for (int i = 0; i < 2; i++)
    gload16(Qp + ((size_t)(q0 + i * 64 + sr) << 6) + scb,
            sm + 16384 + i * 4096 + ldst);
  __syncthreads();                            // Q landed (vmcnt+lgkm drain)
  short8_t aq[2];
  #pragma unroll
  for (int kk = 0; kk < 2; kk++)
    aq[kk] = RDSWZ((sm + 16384), w * 16 + l16, kk * 64 + kg * 16);
  __syncthreads();                            // all waves' Q-reads complete

  f32x4 acc_o[4];
  float m_r[4], l_r[4];
  #pragma unroll
  for (int j = 0; j < 4; j++) {
    m_r[j] = -3e38f; l_r[j] = 0.f;
    #pragma unroll
    for (int n2 = 0; n2 < 4; n2++) acc_o[n2][j] = 0.f;
  }

  const float C = 0.125f * 1.44269504f;       // scale * log2(e)
  const int nkt = qb + 1;
  stageK(0, 0); stageV(0, 0);                 // prologue -> buf0

  for (int kt = 0; kt < nkt; kt++) {
    const int cur = kt & 1;
    if (kt + 1 < nkt) {
      stageK(kt + 1, cur ^ 1); stageV(kt + 1, cur ^ 1);
      asm volatile("s_waitcnt vmcnt(4)" ::: "memory");
    } else {
      asm volatile("s_waitcnt vmcnt(0)" ::: "memory");
    }
    BAR();                                    // tile kt data visible to all

    const short* lK = sm + cur * 16384;
    const short* lV = sm + cur * 16384 + 8192;
    const int k0 = kt << 7;

    // ---- S = Q K^T (log2-domain scale applied later) ----
    f32x4 s[8];
    #pragma unroll
    for (int nf = 0; nf < 8; nf++)
      #pragma unroll
      for (int j = 0; j < 4; j++) s[nf][j] = 0.f;
    #pragma unroll
    for (int kk = 0; kk < 2; kk++)
      #pragma unroll
      for (int nf = 0; nf < 8; nf++) {
        short8_t bk = RDSWZ(lK, nf * 16 + l16, kk * 64 + kg * 16);
        s[nf] = __builtin_amdgcn_mfma_f32_16x16x32_bf16(aq[kk], bk, s[nf], 0, 0, 0);
      }

    // ---- online softmax (exp2 domain) + P~ write ----
    const bool diag = (kt == qb);
    #pragma unroll
    for (int j = 0; j < 4; j++) {
      const int ql = w * 16 + kg * 4 + j;
      const int q = q0 + ql;
      float sv[8]; float tm = -3e38f;
      #pragma unroll
      for (int nf = 0; nf < 8; nf++) {
        const int kv = k0 + nf * 16 + l16;
        const float x = s[nf][j] * C;
        sv[nf] = (!diag || kv <= q) ? x : -3e38f;
        tm = fmaxf(tm, sv[nf]);
      }
      #pragma unroll
      for (int o = 1; o < 16; o <<= 1) tm = fmaxf(tm, __shfl_xor(tm, o));
      const float mn = fmaxf(m_r[j], tm);
      const float scale = exp2f(m_r[j] - mn);
      float ts = 0.f;
      #pragma unroll
      for (int nf = 0; nf < 8; nf++) {
        const float e = exp2f(sv[nf] - mn);
        ts += e;
        lP[(ql << 7) + ((nf * 16 + l16) ^ ((ql & 7) << 3))] = f2bf(e);
      }
      #pragma unroll
      for (int o = 1; o < 16; o <<= 1) ts += __shfl_xor(ts, o);
      l_r[j] = l_r[j] * scale + ts;
      m_r[j] = mn;
      #pragma unroll
      for (int n2 = 0; n2 < 4; n2++) acc_o[n2][j] *= scale;
    }

    // ---- O += P~ V  (P wave-private: rows w*16..w*16+15) ----
    #pragma unroll
    for (int kc = 0; kc < 4; kc++) {
      const int pr = w * 16 + l16;
      short8_t pa = *(const short8_t*)
          &lP[(pr << 7) + ((kc * 32 + kg * 8) ^ ((pr & 7) << 3))];
      #pragma unroll
      for (int n2 = 0; n2 < 4; n2++) {
        short8_t vb = RDSWZ7(lV, n2 * 16 + l16, kc * 64 + kg * 16);
        acc_o[n2] = __builtin_amdgcn_mfma_f32_16x16x32_bf16(pa, vb, acc_o[n2], 0, 0, 0);
      }
    }
    BAR();                 // all waves done with buf cur before its overwrite
  }

  // ---- normalize + write O[b, s, h*64 + hd] ----
  #pragma unroll
  for (int j = 0; j < 4; j++) {
    const int q = q0 + w * 16 + kg * 4 + j;
    const float inv = 1.f / l_r[j];
    #pragma unroll
    for (int n2 = 0; n2 < 4; n2++) {
      const int col = h * HDD + n2 * 16 + l16;
      Og[(((size_t)bidx << 10) + q) * DD + col] = f2bf(acc_o[n2][j] * inv);
    }
  }
}

// ---------------- LayerNorm (D=1024) with optional residual ----------------
template<int ADD_RES, int WRITE_F32>
__global__ __launch_bounds__(256) void k_ln(
    const float* __restrict__ src, const float* __restrict__ res,
    const float* __restrict__ g, const float* __restrict__ b,
    float* __restrict__ of, short* __restrict__ ob) {
  const int row = blockIdx.x;
  const int tid = threadIdx.x;
  float4 v = ((const float4*)(src + ((size_t)row << 10)))[tid];
  float s1 = v.x + v.y + v.z + v.w;
  float s2 = v.x * v.x + v.y * v.y + v.z * v.z + v.w * v.w;
  #pragma unroll
  for (int o = 32; o; o >>= 1) { s1 += __shfl_xor(s1, o); s2 += __shfl_xor(s2, o); }
  __shared__ float sh1[4], sh2[4];
  if ((tid & 63) == 0) { sh1[tid >> 6] = s1; sh2[tid >> 6] = s2; }
  __syncthreads();
  s1 = sh1[0] + sh1[1] + sh1[2] + sh1[3];
  s2 = sh2[0] + sh2[1] + sh2[2] + sh2[3];
  const float mean = s1 * (1.f / 1024.f);
  const float var  = s2 * (1.f / 1024.f) - mean * mean;
  const float rs = rsqrtf(var + 1e-5f);
  float4 gg = ((const float4*)g)[tid];
  float4 bb = ((const float4*)b)[tid];
  float4 o4;
  o4.x = (v.x - mean) * rs * gg.x + bb.x;
  o4.y = (v.y - mean) * rs * gg.y + bb.y;
  o4.z = (v.z - mean) * rs * gg.z + bb.z;
  o4.w = (v.w - mean) * rs * gg.w + bb.w;
  if (ADD_RES) {
    float4 rr = ((const float4*)(res + ((size_t)row << 10)))[tid];
    o4.x += rr.x; o4.y += rr.y; o4.z += rr.z; o4.w += rr.w;
  }
  if (WRITE_F32) ((float4*)(of + ((size_t)row << 10)))[tid] = o4;
  short4 s4; s4.x = f2bf(o4.x); s4.y = f2bf(o4.y);
  s4.z = f2bf(o4.z); s4.w = f2bf(o4.w);
  ((short4*)ob)[((size_t)row << 8) + tid] = s4;
}

extern "C" void kernel_launch(void* const* d_in, const int* in_sizes, int n_in,
                              void* d_out, int out_size, void* d_ws, size_t ws_size,
                              hipStream_t stream) {
  (void)in_sizes; (void)n_in; (void)out_size; (void)ws_size;
  const int*   tokens  = (const int*)d_in[0];
  const float* tok_emb = (const float*)d_in[1];
  const float* pos_emb = (const float*)d_in[2];
  const float* Wq = (const float*)d_in[3];
  const float* Wk = (const float*)d_in[4];
  const float* Wv = (const float*)d_in[5];
  const float* Wp = (const float*)d_in[6];
  const float* ln1s = (const float*)d_in[7];
  const float* ln1b = (const float*)d_in[8];
  const float* W1 = (const float*)d_in[9];
  const float* b1 = (const float*)d_in[10];
  const float* W2 = (const float*)d_in[11];
  const float* b2 = (const float*)d_in[12];
  const float* ln2s = (const float*)d_in[13];
  const float* ln2b = (const float*)d_in[14];
  const float* lnfs = (const float*)d_in[15];
  const float* lnfb = (const float*)d_in[16];
  const float* Wh = (const float*)d_in[17];
  const float* bh = (const float*)d_in[18];
  float* out = (float*)d_out;

  hipFuncSetAttribute((const void*)k_gemm256<6>,
      hipFuncAttributeMaxDynamicSharedMemorySize, 131072);
  hipFuncSetAttribute((const void*)k_gemm256<8>,
      hipFuncAttributeMaxDynamicSharedMemorySize, 131072);
  hipFuncSetAttribute((const void*)k_gemm256<9>,
      hipFuncAttributeMaxDynamicSharedMemorySize, 131072);
  hipFuncSetAttribute((const void*)k_attn,
      hipFuncAttributeMaxDynamicSharedMemorySize, 98304);

  char* p = (char*)d_ws;
  auto alloc = [&](size_t elems, size_t esz) -> char* {
    char* r = p; p += (elems * esz + 255) & ~(size_t)255; return r;
  };
  short* WqkvT = (short*)alloc((size_t)LNUM * 3 * DD * DD, 2);  // [L][3][D][D]
  short* WpT = (short*)alloc((size_t)LNUM * DD * DD, 2);
  short* W1T = (short*)alloc((size_t)LNUM * DD * FF, 2);
  short* W2T = (short*)alloc((size_t)LNUM * DD * FF, 2);
  short* WhT = (short*)alloc((size_t)DD * VV, 2);
  float* xf   = (float*)alloc((size_t)MROWS * DD, 4);   // fp32 residual stream
  float* ff   = (float*)alloc((size_t)MROWS * DD, 4);
  short* xb   = (short*)alloc((size_t)MROWS * DD, 2);
  short* ab   = (short*)alloc((size_t)MROWS * DD, 2);
  short* qkvb = (short*)alloc((size_t)3 * MROWS * DD, 2); // q | k | v^T contiguous
  short* obuf = (short*)alloc((size_t)MROWS * DD, 2);
  short* hb   = (short*)alloc((size_t)MROWS * FF, 2);
  short* xfb  = (short*)alloc((size_t)MROWS * DD, 2);
  short* qb   = qkvb;
  short* kb   = qkvb + (size_t)MROWS * DD;
  short* vtb  = qkvb + (size_t)2 * MROWS * DD;

  dim3 blk(256);
  dim3 t8(32, 8);
  const long long DD2 = (long long)DD * DD;
  k_tcvt<<<dim3(DD / 32, DD / 32, LNUM), t8, 0, stream>>>(Wq, WqkvT,          DD, DD, 3 * DD2);
  k_tcvt<<<dim3(DD / 32, DD / 32, LNUM), t8, 0, stream>>>(Wk, WqkvT + DD2,    DD, DD, 3 * DD2);
  k_tcvt<<<dim3(DD / 32, DD / 32, LNUM), t8, 0, stream>>>(Wv, WqkvT + 2*DD2,  DD, DD, 3 * DD2);
  k_tcvt<<<dim3(DD / 32, DD / 32, LNUM), t8, 0, stream>>>(Wp, WpT, DD, DD, DD2);
  k_tcvt<<<dim3(FF / 32, DD / 32, LNUM), t8, 0, stream>>>(W1, W1T, DD, FF, (long long)DD * FF);
  k_tcvt<<<dim3(DD / 32, FF / 32, LNUM), t8, 0, stream>>>(W2, W2T, FF, DD, (long long)DD * FF);
  k_tcvt<<<dim3(VV / 32, DD / 32, 1),   t8, 0, stream>>>(Wh, WhT, DD, VV, 0);

  k_embed<<<(MROWS * DD / 4) / 256, blk, 0, stream>>>(tokens, tok_emb, pos_emb, xf, xb);

  for (int l = 0; l < LNUM; l++) {
    const short* wqkv = WqkvT + (size_t)l * 3 * DD * DD;
    const short* wp = WpT + (size_t)l * DD * DD;
    const short* w1 = W1T + (size_t)l * DD * FF;
    const short* w2 = W2T + (size_t)l * DD * FF;

    // fused QKV projection: [4096 x 3072 x 1024]
    k_gemm256<8><<<dim3(12, 16), 512, 131072, stream>>>(xb, wqkv, nullptr, qkvb,
        MROWS, 3 * DD, DD, DD, DD);
    // flash attention v2 -> obuf [B,S,D]
    k_attn<<<dim3(8, BB * HH), 512, 98304, stream>>>(qb, kb, vtb, obuf);
    // proj: [4096 x 1024 x 1024] on 2-phase 128^2 (256 wg -> full chip)
    k_gemm<5><<<dim3(8, 32), blk, 0, stream>>>(obuf, wp, nullptr, ff,
        MROWS, DD, DD, DD, DD);
    k_ln<1, 0><<<MROWS, blk, 0, stream>>>(ff, xf, ln1s + (size_t)l * DD,
        ln1b + (size_t)l * DD, nullptr, ab);
    // ffn1: [4096 x 4096 x 1024]
    k_gemm256<6><<<dim3(16, 16), 512, 131072, stream>>>(ab, w1, b1 + (size_t)l * FF, hb,
        MROWS, FF, DD, DD, DD);
    // ffn2: [4096 x 1024 x 4096] on 2-phase 128^2
    k_gemm<7><<<dim3(8, 32), blk, 0, stream>>>(hb, w2, b2 + (size_t)l * DD, ff,
        MROWS, DD, FF, FF, FF);
    k_ln<1, 1><<<MROWS, blk, 0, stream>>>(ff, xf, ln2s + (size_t)l * DD,
        ln2b + (size_t)l * DD, xf, xb);
  }

  k_ln<0, 0><<<MROWS, blk, 0, stream>>>(xf, nullptr, lnfs, lnfb, nullptr, xfb);
  // logits = lnf(x) @ Wh + bh : [4096 x 32000 x 1024], interleaved epilogue
  k_gemm256<9><<<dim3(VV / 256, 16), 512, 131072, stream>>>(xfb, WhT, bh, out,
      MROWS, VV, DD, DD, DD);
}